// Round 4
// baseline (413.454 us; speedup 1.0000x reference)
//
#include <hip/hip_runtime.h>
#include <math.h>

#define NNODES 50000
#define NEDGES 800000
#define NF 128
#define CSR_CAP (NEDGES + 8 * NNODES)   // padded capacity (pad <= 7 per node)
constexpr float LN_EPS = 1e-5f;

__device__ __forceinline__ float clean0(float v) {
    return (isnan(v) || isinf(v)) ? 0.0f : v;
}
__device__ __forceinline__ float cleanw(float v) {
    if (isnan(v)) return 0.0f;
    if (isinf(v)) return v > 0.0f ? 1.0f : 0.0f;
    return v;
}
__device__ __forceinline__ int clampN(int v) {
    return min(max(v, 0), NNODES - 1);
}
__device__ __forceinline__ int pad8(int v) { return (v + 7) & ~7; }

// ---- pass 1: count in-degree, record per-edge rank (1 atomic/edge) ------
__global__ void k_count_rank(const int* __restrict__ ei, int* __restrict__ rank,
                             int* __restrict__ cnt) {
    int e = blockIdx.x * blockDim.x + threadIdx.x;
    if (e >= NEDGES) return;
    int c = clampN(ei[NEDGES + e]);
    rank[e] = atomicAdd(&cnt[c], 1);
}

// ---- 3-kernel exclusive scan of pad8(cnt) -> padded rowptr[N+1] ---------
__global__ void k_scan1(const int* __restrict__ cnt, int* __restrict__ bsum) {
    __shared__ int sm[256];
    int t = threadIdx.x;
    int i = blockIdx.x * 256 + t;
    sm[t] = (i < NNODES) ? pad8(cnt[i]) : 0;
    __syncthreads();
    for (int o = 128; o > 0; o >>= 1) {
        if (t < o) sm[t] += sm[t + o];
        __syncthreads();
    }
    if (t == 0) bsum[blockIdx.x] = sm[0];
}

__global__ void k_scan2(int* __restrict__ bsum, int nb) {
    __shared__ int sm[256];
    int t = threadIdx.x;
    int v = (t < nb) ? bsum[t] : 0;
    sm[t] = v;
    __syncthreads();
    for (int o = 1; o < 256; o <<= 1) {
        int add = (t >= o) ? sm[t - o] : 0;
        __syncthreads();
        sm[t] += add;
        __syncthreads();
    }
    if (t < nb) bsum[t] = sm[t] - v;   // exclusive
}

__global__ void k_scan3(const int* __restrict__ cnt, const int* __restrict__ bsum,
                        int* __restrict__ rowptr) {
    __shared__ int sm[256];
    int t = threadIdx.x;
    int i = blockIdx.x * 256 + t;
    int v = (i < NNODES) ? pad8(cnt[i]) : 0;
    sm[t] = v;
    __syncthreads();
    for (int o = 1; o < 256; o <<= 1) {
        int add = (t >= o) ? sm[t - o] : 0;
        __syncthreads();
        sm[t] += add;
        __syncthreads();
    }
    if (i < NNODES) rowptr[i + 1] = bsum[blockIdx.x] + sm[t];
    if (i == 0) rowptr[0] = 0;
}

// ---- pass 2: atomic-free scatter (src, cleaned w); pads stay (0,0) ------
__global__ void k_scatter(const int* __restrict__ ei, const float* __restrict__ ea,
                          const int* __restrict__ rank, const int* __restrict__ rowptr,
                          int2* __restrict__ csr) {
    int e = blockIdx.x * blockDim.x + threadIdx.x;
    if (e >= NEDGES) return;
    int r = clampN(ei[e]);
    int c = clampN(ei[NEDGES + e]);
    csr[rowptr[c] + rank[e]] = make_int2(r, __float_as_int(cleanw(ea[e])));
}

// ---- deg = 1 + row-sum of w (pads are 0), dis = rsqrt(deg) --------------
__global__ void k_deg_dis(const int2* __restrict__ csr, const int* __restrict__ rowptr,
                          float* __restrict__ dis) {
    int n = blockIdx.x * blockDim.x + threadIdx.x;
    if (n >= NNODES) return;
    int beg = rowptr[n], end = rowptr[n + 1];     // length multiple of 8
    float d = 1.0f;
    for (int p = beg; p + 4 <= end; p += 4) {
        int2 a = csr[p], b = csr[p + 1], c = csr[p + 2], e = csr[p + 3];
        d += __int_as_float(a.y) + __int_as_float(b.y)
           + __int_as_float(c.y) + __int_as_float(e.y);
    }
    dis[n] = (d > 0.0f) ? rsqrtf(d) : 0.0f;
}

// ---- LayerNorm: one wave per node, float2 per lane ----------------------
__global__ void k_layernorm(const float* __restrict__ x, const float* __restrict__ gamma,
                            const float* __restrict__ beta, float* __restrict__ xn) {
    int n = (blockIdx.x * blockDim.x + threadIdx.x) >> 6;
    int lane = threadIdx.x & 63;
    if (n >= NNODES) return;
    float2 v = ((const float2*)(x + (size_t)n * NF))[lane];
    v.x = clean0(v.x); v.y = clean0(v.y);
    float s = v.x + v.y;
    for (int o = 32; o > 0; o >>= 1) s += __shfl_xor(s, o);
    float mu = s * (1.0f / NF);
    float dx = v.x - mu, dy = v.y - mu;
    float q = dx * dx + dy * dy;
    for (int o = 32; o > 0; o >>= 1) q += __shfl_xor(q, o);
    float rstd = rsqrtf(q * (1.0f / NF) + LN_EPS);
    float2 g = ((const float2*)gamma)[lane];
    float2 b = ((const float2*)beta)[lane];
    float2 o2;
    o2.x = dx * rstd * g.x + b.x;
    o2.y = dy * rstd * g.y + b.y;
    ((float2*)(xn + (size_t)n * NF))[lane] = o2;
}

// ---- fp32 GEMM: C[r,:] = dis[r] * (A[r,:] @ W) --------------------------
// float4 A-fragment reads along k: 12 ds_read_b128 per 128 FMAs.
__global__ __launch_bounds__(256) void k_gemm128(const float* __restrict__ A,
                                                 const float* __restrict__ W,
                                                 const float* __restrict__ dis,
                                                 float* __restrict__ C, int M) {
    __shared__ float xs[64][132];   // row stride 132 floats (16B-aligned rows)
    __shared__ float ws[32][128];
    int t = threadIdx.x;
    int row0 = blockIdx.x * 64;

    for (int i = 0; i < 8; i++) {
        int j = t + i * 256;
        int r = j >> 5;
        int c4 = (j & 31) * 4;
        int gr = row0 + r;
        float4 v = make_float4(0.f, 0.f, 0.f, 0.f);
        if (gr < M) v = *(const float4*)(A + (size_t)gr * 128 + c4);
        *(float4*)&xs[r][c4] = v;
    }

    int tx = t & 31, ty = t >> 5;
    int c0 = tx * 4, r0 = ty * 8;
    float acc[8][4];
    #pragma unroll
    for (int j = 0; j < 8; j++)
        for (int q = 0; q < 4; q++) acc[j][q] = 0.0f;

    for (int kk = 0; kk < 4; kk++) {
        __syncthreads();
        for (int i = 0; i < 4; i++) {
            int j = t + i * 256;
            int r = j >> 5;
            int c4 = (j & 31) * 4;
            *(float4*)&ws[r][c4] = *(const float4*)(W + (size_t)(kk * 32 + r) * 128 + c4);
        }
        __syncthreads();
        #pragma unroll
        for (int k4 = 0; k4 < 8; k4++) {
            int kb = kk * 32 + k4 * 4;
            float4 a[8];
            #pragma unroll
            for (int j = 0; j < 8; j++) a[j] = *(const float4*)&xs[r0 + j][kb];
            float4 w0 = *(const float4*)&ws[k4 * 4 + 0][c0];
            float4 w1 = *(const float4*)&ws[k4 * 4 + 1][c0];
            float4 w2 = *(const float4*)&ws[k4 * 4 + 2][c0];
            float4 w3 = *(const float4*)&ws[k4 * 4 + 3][c0];
            #pragma unroll
            for (int j = 0; j < 8; j++) {
                acc[j][0] += a[j].x * w0.x + a[j].y * w1.x + a[j].z * w2.x + a[j].w * w3.x;
                acc[j][1] += a[j].x * w0.y + a[j].y * w1.y + a[j].z * w2.y + a[j].w * w3.y;
                acc[j][2] += a[j].x * w0.z + a[j].y * w1.z + a[j].z * w2.z + a[j].w * w3.z;
                acc[j][3] += a[j].x * w0.w + a[j].y * w1.w + a[j].z * w2.w + a[j].w * w3.w;
            }
        }
    }

    #pragma unroll
    for (int j = 0; j < 8; j++) {
        int gr = row0 + r0 + j;
        if (gr < M) {
            float s = dis[gr];
            float4 v = make_float4(acc[j][0] * s, acc[j][1] * s, acc[j][2] * s, acc[j][3] * s);
            *(float4*)(C + (size_t)gr * 128 + c0) = v;
        }
    }
}

// ---- CSR aggregation: wave/node, padded rows, software-pipelined --------
// h is pre-scaled by dis[src]; out = dis[n]*(h[n] + sum w*h[src]) + bias.
template <bool RELU>
__global__ void k_aggregate(const float* __restrict__ h, const float* __restrict__ dis,
                            const int* __restrict__ rowptr, const int2* __restrict__ csr,
                            const float* __restrict__ bias, float* __restrict__ out) {
    int n0 = (blockIdx.x * blockDim.x + threadIdx.x) >> 6;
    if (n0 >= NNODES) return;
    int n = __builtin_amdgcn_readfirstlane(n0);
    int lane = threadIdx.x & 63;
    const float2* hl = (const float2*)h + lane;        // row stride 64 float2
    float2 acc = hl[(size_t)n * 64];                   // self term (pre-scaled)
    int beg = rowptr[n], end = rowptr[n + 1];          // multiple of 8
    int p = beg;
    if (p < end) {
        int2 rec[8];
        #pragma unroll
        for (int j = 0; j < 8; j++) rec[j] = csr[p + j];
        p += 8;
        while (p < end) {
            float2 v[8];
            #pragma unroll
            for (int j = 0; j < 8; j++) v[j] = hl[(size_t)rec[j].x * 64];
            int2 rec2[8];
            #pragma unroll
            for (int j = 0; j < 8; j++) rec2[j] = csr[p + j];
            #pragma unroll
            for (int j = 0; j < 8; j++) {
                float w = __int_as_float(rec[j].y);
                acc.x += v[j].x * w;
                acc.y += v[j].y * w;
            }
            #pragma unroll
            for (int j = 0; j < 8; j++) rec[j] = rec2[j];
            p += 8;
        }
        float2 v[8];
        #pragma unroll
        for (int j = 0; j < 8; j++) v[j] = hl[(size_t)rec[j].x * 64];
        #pragma unroll
        for (int j = 0; j < 8; j++) {
            float w = __int_as_float(rec[j].y);
            acc.x += v[j].x * w;
            acc.y += v[j].y * w;
        }
    }
    float dn = dis[n];
    float2 b = ((const float2*)bias)[lane];
    acc.x = acc.x * dn + b.x;
    acc.y = acc.y * dn + b.y;
    if (RELU) { acc.x = fmaxf(acc.x, 0.0f); acc.y = fmaxf(acc.y, 0.0f); }
    ((float2*)(out + (size_t)n * NF))[lane] = acc;
}

// ---- GEMV: h3[n] = dis[n] * dot(X[n,:], W3[:,0]) ------------------------
__global__ void k_gemv128(const float* __restrict__ X, const float* __restrict__ W3,
                          const float* __restrict__ dis, float* __restrict__ h3) {
    int n = (blockIdx.x * blockDim.x + threadIdx.x) >> 6;
    int lane = threadIdx.x & 63;
    if (n >= NNODES) return;
    float2 v = ((const float2*)(X + (size_t)n * NF))[lane];
    float2 w = ((const float2*)W3)[lane];
    float s = v.x * w.x + v.y * w.y;
    for (int o = 32; o > 0; o >>= 1) s += __shfl_xor(s, o);
    if (lane == 0) h3[n] = s * dis[n];
}

// ---- scalar aggregation for output layer (padded rows) ------------------
__global__ void k_agg_scalar(const float* __restrict__ h3, const float* __restrict__ dis,
                             const int* __restrict__ rowptr, const int2* __restrict__ csr,
                             const float* __restrict__ b3, float* __restrict__ out) {
    int n = blockIdx.x * blockDim.x + threadIdx.x;
    if (n >= NNODES) return;
    float acc = h3[n];
    int beg = rowptr[n], end = rowptr[n + 1];
    for (int p = beg; p + 4 <= end; p += 4) {
        int2 e0 = csr[p], e1 = csr[p + 1], e2 = csr[p + 2], e3 = csr[p + 3];
        float v0 = h3[e0.x], v1 = h3[e1.x], v2 = h3[e2.x], v3 = h3[e3.x];
        acc += v0 * __int_as_float(e0.y) + v1 * __int_as_float(e1.y)
             + v2 * __int_as_float(e2.y) + v3 * __int_as_float(e3.y);
    }
    out[n] = acc * dis[n] + b3[0];
}

extern "C" void kernel_launch(void* const* d_in, const int* in_sizes, int n_in,
                              void* d_out, int out_size, void* d_ws, size_t ws_size,
                              hipStream_t stream) {
    const float* x  = (const float*)d_in[0];
    const int*   ei = (const int*)d_in[1];
    const float* ea = (const float*)d_in[2];
    const float* g  = (const float*)d_in[3];
    const float* be = (const float*)d_in[4];
    const float* W1 = (const float*)d_in[5];
    const float* b1 = (const float*)d_in[6];
    const float* W2 = (const float*)d_in[7];
    const float* b2 = (const float*)d_in[8];
    const float* W3 = (const float*)d_in[9];
    const float* b3 = (const float*)d_in[10];
    float* out = (float*)d_out;

    char* ws = (char*)d_ws;
    size_t off = 0;
    auto alloc = [&](size_t bytes) {
        void* p = ws + off;
        off += (bytes + 255) & ~((size_t)255);
        return p;
    };
    float* bufA   = (float*)alloc((size_t)NNODES * NF * 4);
    float* bufB   = (float*)alloc((size_t)NNODES * NF * 4);
    int*   rank   = (int*)  alloc((size_t)NEDGES * 4);
    float* dis    = (float*)alloc((size_t)NNODES * 4);
    int*   cnt    = (int*)  alloc((size_t)NNODES * 4);
    int*   rowptr = (int*)  alloc((size_t)(NNODES + 1) * 4);
    int2*  csr    = (int2*) alloc((size_t)CSR_CAP * 8);
    int*   bsum   = (int*)  alloc(256 * 4);
    float* h3     = (float*)alloc((size_t)NNODES * 4);
    (void)ws_size; (void)in_sizes; (void)n_in; (void)out_size;

    const int NB_N = (NNODES + 255) / 256;      // 196
    const int NB_E = (NEDGES + 255) / 256;      // 3125
    const int NB_W = (NNODES * 64 + 255) / 256; // 12500 (wave per node)
    const int NB_G = (NNODES + 63) / 64;        // 782  (gemm 64-row tiles)

    hipMemsetAsync(cnt, 0, (size_t)NNODES * 4, stream);
    hipMemsetAsync(csr, 0, (size_t)CSR_CAP * 8, stream);
    k_count_rank<<<NB_E, 256, 0, stream>>>(ei, rank, cnt);
    k_scan1<<<NB_N, 256, 0, stream>>>(cnt, bsum);
    k_scan2<<<1, 256, 0, stream>>>(bsum, NB_N);
    k_scan3<<<NB_N, 256, 0, stream>>>(cnt, bsum, rowptr);
    k_scatter<<<NB_E, 256, 0, stream>>>(ei, ea, rank, rowptr, csr);
    k_deg_dis<<<NB_N, 256, 0, stream>>>(csr, rowptr, dis);

    k_layernorm<<<NB_W, 256, 0, stream>>>(x, g, be, bufA);

    // layer 1
    k_gemm128<<<NB_G, 256, 0, stream>>>(bufA, W1, dis, bufB, NNODES);
    k_aggregate<true><<<NB_W, 256, 0, stream>>>(bufB, dis, rowptr, csr, b1, bufA);
    // layer 2
    k_gemm128<<<NB_G, 256, 0, stream>>>(bufA, W2, dis, bufB, NNODES);
    k_aggregate<true><<<NB_W, 256, 0, stream>>>(bufB, dis, rowptr, csr, b2, bufA);
    // layer 3
    k_gemv128<<<NB_W, 256, 0, stream>>>(bufA, W3, dis, h3);
    k_agg_scalar<<<NB_N, 256, 0, stream>>>(h3, dis, rowptr, csr, b3, out);
}

// Round 5
// 367.871 us; speedup vs baseline: 1.1239x; 1.1239x over previous
//
#include <hip/hip_runtime.h>
#include <math.h>

#define NNODES 50000
#define NEDGES 800000
#define NF 128
#define CSR_CAP (NEDGES + 8 * NNODES)   // padded capacity (pad <= 7 per node)
constexpr float LN_EPS = 1e-5f;

typedef short v8s __attribute__((ext_vector_type(8)));
typedef float v4f __attribute__((ext_vector_type(4)));

__device__ __forceinline__ float clean0(float v) {
    return (isnan(v) || isinf(v)) ? 0.0f : v;
}
__device__ __forceinline__ float cleanw(float v) {
    if (isnan(v)) return 0.0f;
    if (isinf(v)) return v > 0.0f ? 1.0f : 0.0f;
    return v;
}
__device__ __forceinline__ int clampN(int v) {
    return min(max(v, 0), NNODES - 1);
}
__device__ __forceinline__ int pad8(int v) { return (v + 7) & ~7; }

// bf16 helpers (RNE)
__device__ __forceinline__ unsigned short f2bf(float f) {
    unsigned int u = __float_as_uint(f);
    return (unsigned short)((u + 0x7FFFu + ((u >> 16) & 1u)) >> 16);
}
__device__ __forceinline__ float bf2f(unsigned short h) {
    return __uint_as_float(((unsigned int)h) << 16);
}
__device__ __forceinline__ void split_bf(float v, unsigned short& h, unsigned short& l) {
    h = f2bf(v);
    l = f2bf(v - bf2f(h));
}

// ---- pass 1: count in-degree, record per-edge rank (1 atomic/edge) ------
__global__ void k_count_rank(const int* __restrict__ ei, int* __restrict__ rank,
                             int* __restrict__ cnt) {
    int e = blockIdx.x * blockDim.x + threadIdx.x;
    if (e >= NEDGES) return;
    int c = clampN(ei[NEDGES + e]);
    rank[e] = atomicAdd(&cnt[c], 1);
}

// ---- 3-kernel exclusive scan of pad8(cnt) -> padded rowptr[N+1] ---------
__global__ void k_scan1(const int* __restrict__ cnt, int* __restrict__ bsum) {
    __shared__ int sm[256];
    int t = threadIdx.x;
    int i = blockIdx.x * 256 + t;
    sm[t] = (i < NNODES) ? pad8(cnt[i]) : 0;
    __syncthreads();
    for (int o = 128; o > 0; o >>= 1) {
        if (t < o) sm[t] += sm[t + o];
        __syncthreads();
    }
    if (t == 0) bsum[blockIdx.x] = sm[0];
}

__global__ void k_scan2(int* __restrict__ bsum, int nb) {
    __shared__ int sm[256];
    int t = threadIdx.x;
    int v = (t < nb) ? bsum[t] : 0;
    sm[t] = v;
    __syncthreads();
    for (int o = 1; o < 256; o <<= 1) {
        int add = (t >= o) ? sm[t - o] : 0;
        __syncthreads();
        sm[t] += add;
        __syncthreads();
    }
    if (t < nb) bsum[t] = sm[t] - v;   // exclusive
}

__global__ void k_scan3(const int* __restrict__ cnt, const int* __restrict__ bsum,
                        int* __restrict__ rowptr) {
    __shared__ int sm[256];
    int t = threadIdx.x;
    int i = blockIdx.x * 256 + t;
    int v = (i < NNODES) ? pad8(cnt[i]) : 0;
    sm[t] = v;
    __syncthreads();
    for (int o = 1; o < 256; o <<= 1) {
        int add = (t >= o) ? sm[t - o] : 0;
        __syncthreads();
        sm[t] += add;
        __syncthreads();
    }
    if (i < NNODES) rowptr[i + 1] = bsum[blockIdx.x] + sm[t];
    if (i == 0) rowptr[0] = 0;
}

// ---- pass 2: atomic-free scatter (src, cleaned w); pads stay (0,0) ------
__global__ void k_scatter(const int* __restrict__ ei, const float* __restrict__ ea,
                          const int* __restrict__ rank, const int* __restrict__ rowptr,
                          int2* __restrict__ csr) {
    int e = blockIdx.x * blockDim.x + threadIdx.x;
    if (e >= NEDGES) return;
    int r = clampN(ei[e]);
    int c = clampN(ei[NEDGES + e]);
    csr[rowptr[c] + rank[e]] = make_int2(r, __float_as_int(cleanw(ea[e])));
}

// ---- deg = 1 + row-sum of w (pads are 0), dis = rsqrt(deg) --------------
__global__ void k_deg_dis(const int2* __restrict__ csr, const int* __restrict__ rowptr,
                          float* __restrict__ dis) {
    int n = blockIdx.x * blockDim.x + threadIdx.x;
    if (n >= NNODES) return;
    int beg = rowptr[n], end = rowptr[n + 1];     // length multiple of 8
    float d = 1.0f;
    for (int p = beg; p + 4 <= end; p += 4) {
        int2 a = csr[p], b = csr[p + 1], c = csr[p + 2], e = csr[p + 3];
        d += __int_as_float(a.y) + __int_as_float(b.y)
           + __int_as_float(c.y) + __int_as_float(e.y);
    }
    dis[n] = (d > 0.0f) ? rsqrtf(d) : 0.0f;
}

// ---- weight prep: split W (128x128) into bf16 hi/lo, TRANSPOSED [n][k] --
__global__ void k_wprep(const float* __restrict__ W1, const float* __restrict__ W2,
                        unsigned short* __restrict__ Wh1T, unsigned short* __restrict__ Wl1T,
                        unsigned short* __restrict__ Wh2T, unsigned short* __restrict__ Wl2T) {
    int nb = blockIdx.x;
    const float* W = (nb < 128) ? W1 : W2;
    unsigned short* Wh = (nb < 128) ? Wh1T : Wh2T;
    unsigned short* Wl = (nb < 128) ? Wl1T : Wl2T;
    int n = nb & 127;
    int k = threadIdx.x;
    float v = W[k * 128 + n];
    unsigned short h, l;
    split_bf(v, h, l);
    Wh[n * 128 + k] = h;
    Wl[n * 128 + k] = l;
}

// ---- LayerNorm: one wave per node; writes split bf16 hi/lo --------------
__global__ void k_layernorm(const float* __restrict__ x, const float* __restrict__ gamma,
                            const float* __restrict__ beta,
                            unsigned short* __restrict__ xh, unsigned short* __restrict__ xl) {
    int n = (blockIdx.x * blockDim.x + threadIdx.x) >> 6;
    int lane = threadIdx.x & 63;
    if (n >= NNODES) return;
    float2 v = ((const float2*)(x + (size_t)n * NF))[lane];
    v.x = clean0(v.x); v.y = clean0(v.y);
    float s = v.x + v.y;
    for (int o = 32; o > 0; o >>= 1) s += __shfl_xor(s, o);
    float mu = s * (1.0f / NF);
    float dx = v.x - mu, dy = v.y - mu;
    float q = dx * dx + dy * dy;
    for (int o = 32; o > 0; o >>= 1) q += __shfl_xor(q, o);
    float rstd = rsqrtf(q * (1.0f / NF) + LN_EPS);
    float2 g = ((const float2*)gamma)[lane];
    float2 b = ((const float2*)beta)[lane];
    float ox = dx * rstd * g.x + b.x;
    float oy = dy * rstd * g.y + b.y;
    ushort2 hh, ll;
    split_bf(ox, hh.x, ll.x);
    split_bf(oy, hh.y, ll.y);
    ((ushort2*)(xh + (size_t)n * NF))[lane] = hh;
    ((ushort2*)(xl + (size_t)n * NF))[lane] = ll;
}

// ---- MFMA GEMM: C[r,:] = dis[r] * ((Ah+Al) @ (Wh+Wl)) -------------------
// Split-bf16 3-product emulation; no LDS; wave owns 16 rows x 128 cols.
__global__ __launch_bounds__(256) void k_gemm_mfma(
        const unsigned short* __restrict__ Ah, const unsigned short* __restrict__ Al,
        const unsigned short* __restrict__ BhT, const unsigned short* __restrict__ BlT,
        const float* __restrict__ dis, float* __restrict__ C) {
    int w = threadIdx.x >> 6;
    int lane = threadIdx.x & 63;
    int m = lane & 15;           // A row within tile / B,C col within tile
    int q = lane >> 4;           // quad
    int rowbase = blockIdx.x * 64 + w * 16;
    int arow = min(rowbase + m, NNODES - 1);

    const v8s* ap = (const v8s*)(Ah + (size_t)arow * NF);
    const v8s* alp = (const v8s*)(Al + (size_t)arow * NF);
    v8s afh[4], afl[4];
    #pragma unroll
    for (int c = 0; c < 4; c++) { afh[c] = ap[c * 4 + q]; afl[c] = alp[c * 4 + q]; }

    float ds[4];
    #pragma unroll
    for (int r = 0; r < 4; r++) ds[r] = dis[min(rowbase + q * 4 + r, NNODES - 1)];

    for (int nt = 0; nt < 8; nt++) {
        int n0 = nt * 16;
        const v8s* bhp = (const v8s*)(BhT + (size_t)(n0 + m) * NF);
        const v8s* blp = (const v8s*)(BlT + (size_t)(n0 + m) * NF);
        v4f acc = {0.f, 0.f, 0.f, 0.f};
        #pragma unroll
        for (int c = 0; c < 4; c++) {
            v8s bh = bhp[c * 4 + q];
            v8s bl = blp[c * 4 + q];
            acc = __builtin_amdgcn_mfma_f32_16x16x32_bf16(afh[c], bh, acc, 0, 0, 0);
            acc = __builtin_amdgcn_mfma_f32_16x16x32_bf16(afh[c], bl, acc, 0, 0, 0);
            acc = __builtin_amdgcn_mfma_f32_16x16x32_bf16(afl[c], bh, acc, 0, 0, 0);
        }
        #pragma unroll
        for (int r = 0; r < 4; r++) {
            int gr = rowbase + q * 4 + r;
            if (gr < NNODES) C[(size_t)gr * NF + n0 + m] = acc[r] * ds[r];
        }
    }
}

// ---- CSR aggregation: wave/node, padded rows, pipelined; split output ---
__global__ void k_aggregate(const float* __restrict__ h, const float* __restrict__ dis,
                            const int* __restrict__ rowptr, const int2* __restrict__ csr,
                            const float* __restrict__ bias,
                            unsigned short* __restrict__ yh, unsigned short* __restrict__ yl) {
    int n0 = (blockIdx.x * blockDim.x + threadIdx.x) >> 6;
    if (n0 >= NNODES) return;
    int n = __builtin_amdgcn_readfirstlane(n0);
    int lane = threadIdx.x & 63;
    const float2* hl = (const float2*)h + lane;        // row stride 64 float2
    float2 acc = hl[(size_t)n * 64];                   // self term (pre-scaled)
    int beg = rowptr[n], end = rowptr[n + 1];          // multiple of 8
    int p = beg;
    if (p < end) {
        int2 rec[8];
        #pragma unroll
        for (int j = 0; j < 8; j++) rec[j] = csr[p + j];
        p += 8;
        while (p < end) {
            float2 v[8];
            #pragma unroll
            for (int j = 0; j < 8; j++) v[j] = hl[(size_t)rec[j].x * 64];
            int2 rec2[8];
            #pragma unroll
            for (int j = 0; j < 8; j++) rec2[j] = csr[p + j];
            #pragma unroll
            for (int j = 0; j < 8; j++) {
                float w = __int_as_float(rec[j].y);
                acc.x += v[j].x * w;
                acc.y += v[j].y * w;
            }
            #pragma unroll
            for (int j = 0; j < 8; j++) rec[j] = rec2[j];
            p += 8;
        }
        float2 v[8];
        #pragma unroll
        for (int j = 0; j < 8; j++) v[j] = hl[(size_t)rec[j].x * 64];
        #pragma unroll
        for (int j = 0; j < 8; j++) {
            float w = __int_as_float(rec[j].y);
            acc.x += v[j].x * w;
            acc.y += v[j].y * w;
        }
    }
    float dn = dis[n];
    float2 b = ((const float2*)bias)[lane];
    float ox = fmaxf(acc.x * dn + b.x, 0.0f);
    float oy = fmaxf(acc.y * dn + b.y, 0.0f);
    ushort2 hh, ll;
    split_bf(ox, hh.x, ll.x);
    split_bf(oy, hh.y, ll.y);
    ((ushort2*)(yh + (size_t)n * NF))[lane] = hh;
    ((ushort2*)(yl + (size_t)n * NF))[lane] = ll;
}

// ---- GEMV from split input: h3[n] = dis[n] * dot(Zh+Zl, W3) -------------
__global__ void k_gemv128(const unsigned short* __restrict__ Zh,
                          const unsigned short* __restrict__ Zl,
                          const float* __restrict__ W3,
                          const float* __restrict__ dis, float* __restrict__ h3) {
    int n = (blockIdx.x * blockDim.x + threadIdx.x) >> 6;
    int lane = threadIdx.x & 63;
    if (n >= NNODES) return;
    ushort2 zh = ((const ushort2*)(Zh + (size_t)n * NF))[lane];
    ushort2 zl = ((const ushort2*)(Zl + (size_t)n * NF))[lane];
    float vx = bf2f(zh.x) + bf2f(zl.x);
    float vy = bf2f(zh.y) + bf2f(zl.y);
    float2 w = ((const float2*)W3)[lane];
    float s = vx * w.x + vy * w.y;
    for (int o = 32; o > 0; o >>= 1) s += __shfl_xor(s, o);
    if (lane == 0) h3[n] = s * dis[n];
}

// ---- scalar aggregation for output layer (padded rows) ------------------
__global__ void k_agg_scalar(const float* __restrict__ h3, const float* __restrict__ dis,
                             const int* __restrict__ rowptr, const int2* __restrict__ csr,
                             const float* __restrict__ b3, float* __restrict__ out) {
    int n = blockIdx.x * blockDim.x + threadIdx.x;
    if (n >= NNODES) return;
    float acc = h3[n];
    int beg = rowptr[n], end = rowptr[n + 1];
    for (int p = beg; p + 4 <= end; p += 4) {
        int2 e0 = csr[p], e1 = csr[p + 1], e2 = csr[p + 2], e3 = csr[p + 3];
        float v0 = h3[e0.x], v1 = h3[e1.x], v2 = h3[e2.x], v3 = h3[e3.x];
        acc += v0 * __int_as_float(e0.y) + v1 * __int_as_float(e1.y)
             + v2 * __int_as_float(e2.y) + v3 * __int_as_float(e3.y);
    }
    out[n] = acc * dis[n] + b3[0];
}

extern "C" void kernel_launch(void* const* d_in, const int* in_sizes, int n_in,
                              void* d_out, int out_size, void* d_ws, size_t ws_size,
                              hipStream_t stream) {
    const float* x  = (const float*)d_in[0];
    const int*   ei = (const int*)d_in[1];
    const float* ea = (const float*)d_in[2];
    const float* g  = (const float*)d_in[3];
    const float* be = (const float*)d_in[4];
    const float* W1 = (const float*)d_in[5];
    const float* b1 = (const float*)d_in[6];
    const float* W2 = (const float*)d_in[7];
    const float* b2 = (const float*)d_in[8];
    const float* W3 = (const float*)d_in[9];
    const float* b3 = (const float*)d_in[10];
    float* out = (float*)d_out;

    char* ws = (char*)d_ws;
    size_t off = 0;
    auto alloc = [&](size_t bytes) {
        void* p = ws + off;
        off += (bytes + 255) & ~((size_t)255);
        return p;
    };
    unsigned short* ah0 = (unsigned short*)alloc((size_t)NNODES * NF * 2);
    unsigned short* al0 = (unsigned short*)alloc((size_t)NNODES * NF * 2);
    unsigned short* ah1 = (unsigned short*)alloc((size_t)NNODES * NF * 2);
    unsigned short* al1 = (unsigned short*)alloc((size_t)NNODES * NF * 2);
    float* bufH   = (float*)alloc((size_t)NNODES * NF * 4);
    int*   rank   = (int*)  alloc((size_t)NEDGES * 4);
    float* dis    = (float*)alloc((size_t)NNODES * 4);
    int*   cnt    = (int*)  alloc((size_t)NNODES * 4);
    int*   rowptr = (int*)  alloc((size_t)(NNODES + 1) * 4);
    int2*  csr    = (int2*) alloc((size_t)CSR_CAP * 8);
    int*   bsum   = (int*)  alloc(256 * 4);
    float* h3     = (float*)alloc((size_t)NNODES * 4);
    unsigned short* Wh1T = (unsigned short*)alloc(128 * 128 * 2);
    unsigned short* Wl1T = (unsigned short*)alloc(128 * 128 * 2);
    unsigned short* Wh2T = (unsigned short*)alloc(128 * 128 * 2);
    unsigned short* Wl2T = (unsigned short*)alloc(128 * 128 * 2);
    (void)ws_size; (void)in_sizes; (void)n_in; (void)out_size;

    const int NB_N = (NNODES + 255) / 256;      // 196
    const int NB_E = (NEDGES + 255) / 256;      // 3125
    const int NB_W = (NNODES * 64 + 255) / 256; // 12500 (wave per node)
    const int NB_G = (NNODES + 63) / 64;        // 782  (gemm 64-row tiles)

    hipMemsetAsync(cnt, 0, (size_t)NNODES * 4, stream);
    hipMemsetAsync(csr, 0, (size_t)CSR_CAP * 8, stream);
    k_count_rank<<<NB_E, 256, 0, stream>>>(ei, rank, cnt);
    k_scan1<<<NB_N, 256, 0, stream>>>(cnt, bsum);
    k_scan2<<<1, 256, 0, stream>>>(bsum, NB_N);
    k_scan3<<<NB_N, 256, 0, stream>>>(cnt, bsum, rowptr);
    k_scatter<<<NB_E, 256, 0, stream>>>(ei, ea, rank, rowptr, csr);
    k_deg_dis<<<NB_N, 256, 0, stream>>>(csr, rowptr, dis);
    k_wprep<<<256, 128, 0, stream>>>(W1, W2, Wh1T, Wl1T, Wh2T, Wl2T);

    k_layernorm<<<NB_W, 256, 0, stream>>>(x, g, be, ah0, al0);

    // layer 1
    k_gemm_mfma<<<NB_G, 256, 0, stream>>>(ah0, al0, Wh1T, Wl1T, dis, bufH);
    k_aggregate<<<NB_W, 256, 0, stream>>>(bufH, dis, rowptr, csr, b1, ah1, al1);
    // layer 2
    k_gemm_mfma<<<NB_G, 256, 0, stream>>>(ah1, al1, Wh2T, Wl2T, dis, bufH);
    k_aggregate<<<NB_W, 256, 0, stream>>>(bufH, dis, rowptr, csr, b2, ah0, al0);
    // layer 3
    k_gemv128<<<NB_W, 256, 0, stream>>>(ah0, al0, W3, dis, h3);
    k_agg_scalar<<<NB_N, 256, 0, stream>>>(h3, dis, rowptr, csr, b3, out);
}

// Round 6
// 364.769 us; speedup vs baseline: 1.1335x; 1.0085x over previous
//
#include <hip/hip_runtime.h>
#include <math.h>

#define NNODES 50000
#define NEDGES 800000
#define NF 128
#define CSR_CAP (NEDGES + 8 * NNODES)   // padded capacity (pad <= 7 per node)
constexpr float LN_EPS = 1e-5f;

typedef short v8s __attribute__((ext_vector_type(8)));
typedef float v4f __attribute__((ext_vector_type(4)));

__device__ __forceinline__ float clean0(float v) {
    return (isnan(v) || isinf(v)) ? 0.0f : v;
}
__device__ __forceinline__ float cleanw(float v) {
    if (isnan(v)) return 0.0f;
    if (isinf(v)) return v > 0.0f ? 1.0f : 0.0f;
    return v;
}
__device__ __forceinline__ int clampN(int v) {
    return min(max(v, 0), NNODES - 1);
}
__device__ __forceinline__ int pad8(int v) { return (v + 7) & ~7; }

// bf16 helpers (RNE)
__device__ __forceinline__ unsigned short f2bf(float f) {
    unsigned int u = __float_as_uint(f);
    return (unsigned short)((u + 0x7FFFu + ((u >> 16) & 1u)) >> 16);
}
__device__ __forceinline__ float bf2f(unsigned short h) {
    return __uint_as_float(((unsigned int)h) << 16);
}
__device__ __forceinline__ void split_bf(float v, unsigned short& h, unsigned short& l) {
    h = f2bf(v);
    l = f2bf(v - bf2f(h));
}

// ---- pass 1: count in-degree, record per-edge rank (1 atomic/edge) ------
__global__ void k_count_rank(const int* __restrict__ ei, int* __restrict__ rank,
                             int* __restrict__ cnt) {
    int e = blockIdx.x * blockDim.x + threadIdx.x;
    if (e >= NEDGES) return;
    int c = clampN(ei[NEDGES + e]);
    rank[e] = atomicAdd(&cnt[c], 1);
}

// ---- 3-kernel exclusive scan of pad8(cnt) -> padded rowptr[N+1] ---------
__global__ void k_scan1(const int* __restrict__ cnt, int* __restrict__ bsum) {
    __shared__ int sm[256];
    int t = threadIdx.x;
    int i = blockIdx.x * 256 + t;
    sm[t] = (i < NNODES) ? pad8(cnt[i]) : 0;
    __syncthreads();
    for (int o = 128; o > 0; o >>= 1) {
        if (t < o) sm[t] += sm[t + o];
        __syncthreads();
    }
    if (t == 0) bsum[blockIdx.x] = sm[0];
}

__global__ void k_scan2(int* __restrict__ bsum, int nb) {
    __shared__ int sm[256];
    int t = threadIdx.x;
    int v = (t < nb) ? bsum[t] : 0;
    sm[t] = v;
    __syncthreads();
    for (int o = 1; o < 256; o <<= 1) {
        int add = (t >= o) ? sm[t - o] : 0;
        __syncthreads();
        sm[t] += add;
        __syncthreads();
    }
    if (t < nb) bsum[t] = sm[t] - v;   // exclusive
}

__global__ void k_scan3(const int* __restrict__ cnt, const int* __restrict__ bsum,
                        int* __restrict__ rowptr) {
    __shared__ int sm[256];
    int t = threadIdx.x;
    int i = blockIdx.x * 256 + t;
    int v = (i < NNODES) ? pad8(cnt[i]) : 0;
    sm[t] = v;
    __syncthreads();
    for (int o = 1; o < 256; o <<= 1) {
        int add = (t >= o) ? sm[t - o] : 0;
        __syncthreads();
        sm[t] += add;
        __syncthreads();
    }
    if (i < NNODES) rowptr[i + 1] = bsum[blockIdx.x] + sm[t];
    if (i == 0) rowptr[0] = 0;
}

// ---- pass 2: atomic-free scatter (src, cleaned w) -----------------------
__global__ void k_scatter(const int* __restrict__ ei, const float* __restrict__ ea,
                          const int* __restrict__ rank, const int* __restrict__ rowptr,
                          int2* __restrict__ csr) {
    int e = blockIdx.x * blockDim.x + threadIdx.x;
    if (e >= NEDGES) return;
    int r = clampN(ei[e]);
    int c = clampN(ei[NEDGES + e]);
    csr[rowptr[c] + rank[e]] = make_int2(r, __float_as_int(cleanw(ea[e])));
}

// ---- merged prep: deg/dis + explicit pad fill + weight split/transpose --
// blocks [0, NB_N): per-node deg = 1 + sum w over real entries; write pads.
// blocks [NB_N, NB_N+128): split W1/W2 into bf16 hi/lo transposed [n][k].
__global__ void k_prep(const int2* __restrict__ csrc, int2* __restrict__ csr,
                       const int* __restrict__ rowptr, const int* __restrict__ cnt,
                       float* __restrict__ dis,
                       const float* __restrict__ W1, const float* __restrict__ W2,
                       unsigned short* __restrict__ Wh1T, unsigned short* __restrict__ Wl1T,
                       unsigned short* __restrict__ Wh2T, unsigned short* __restrict__ Wl2T,
                       int nbn) {
    if ((int)blockIdx.x < nbn) {
        int n = blockIdx.x * 256 + threadIdx.x;
        if (n >= NNODES) return;
        int beg = rowptr[n];
        int c = cnt[n];
        float d = 1.0f;
        for (int p = beg; p < beg + c; p++) d += __int_as_float(csrc[p].y);
        for (int p = beg + c; p < beg + pad8(c); p++) csr[p] = make_int2(0, 0);
        dis[n] = (d > 0.0f) ? rsqrtf(d) : 0.0f;
    } else {
        int idx = (blockIdx.x - nbn) * 256 + threadIdx.x;   // [0, 32768)
        int m = idx >> 14;                                  // which matrix
        int n = (idx >> 7) & 127;
        int k = idx & 127;
        const float* W = m ? W2 : W1;
        unsigned short* Wh = m ? Wh2T : Wh1T;
        unsigned short* Wl = m ? Wl2T : Wl1T;
        unsigned short h, l;
        split_bf(W[k * 128 + n], h, l);
        Wh[n * 128 + k] = h;
        Wl[n * 128 + k] = l;
    }
}

// ---- LayerNorm: one wave per node; writes split bf16 hi/lo --------------
__global__ void k_layernorm(const float* __restrict__ x, const float* __restrict__ gamma,
                            const float* __restrict__ beta,
                            unsigned short* __restrict__ xh, unsigned short* __restrict__ xl) {
    int n = (blockIdx.x * blockDim.x + threadIdx.x) >> 6;
    int lane = threadIdx.x & 63;
    if (n >= NNODES) return;
    float2 v = ((const float2*)(x + (size_t)n * NF))[lane];
    v.x = clean0(v.x); v.y = clean0(v.y);
    float s = v.x + v.y;
    for (int o = 32; o > 0; o >>= 1) s += __shfl_xor(s, o);
    float mu = s * (1.0f / NF);
    float dx = v.x - mu, dy = v.y - mu;
    float q = dx * dx + dy * dy;
    for (int o = 32; o > 0; o >>= 1) q += __shfl_xor(q, o);
    float rstd = rsqrtf(q * (1.0f / NF) + LN_EPS);
    float2 g = ((const float2*)gamma)[lane];
    float2 b = ((const float2*)beta)[lane];
    float ox = dx * rstd * g.x + b.x;
    float oy = dy * rstd * g.y + b.y;
    ushort2 hh, ll;
    split_bf(ox, hh.x, ll.x);
    split_bf(oy, hh.y, ll.y);
    ((ushort2*)(xh + (size_t)n * NF))[lane] = hh;
    ((ushort2*)(xl + (size_t)n * NF))[lane] = ll;
}

// ---- MFMA GEMM: C[r,:] = dis[r] * ((Ah+Al) @ (Wh+Wl)) -------------------
__global__ __launch_bounds__(256) void k_gemm_mfma(
        const unsigned short* __restrict__ Ah, const unsigned short* __restrict__ Al,
        const unsigned short* __restrict__ BhT, const unsigned short* __restrict__ BlT,
        const float* __restrict__ dis, float* __restrict__ C) {
    int w = threadIdx.x >> 6;
    int lane = threadIdx.x & 63;
    int m = lane & 15;           // A row within tile / B,C col within tile
    int q = lane >> 4;           // quad
    int rowbase = blockIdx.x * 64 + w * 16;
    int arow = min(rowbase + m, NNODES - 1);

    const v8s* ap = (const v8s*)(Ah + (size_t)arow * NF);
    const v8s* alp = (const v8s*)(Al + (size_t)arow * NF);
    v8s afh[4], afl[4];
    #pragma unroll
    for (int c = 0; c < 4; c++) { afh[c] = ap[c * 4 + q]; afl[c] = alp[c * 4 + q]; }

    float ds[4];
    #pragma unroll
    for (int r = 0; r < 4; r++) ds[r] = dis[min(rowbase + q * 4 + r, NNODES - 1)];

    for (int nt = 0; nt < 8; nt++) {
        int n0 = nt * 16;
        const v8s* bhp = (const v8s*)(BhT + (size_t)(n0 + m) * NF);
        const v8s* blp = (const v8s*)(BlT + (size_t)(n0 + m) * NF);
        v4f acc = {0.f, 0.f, 0.f, 0.f};
        #pragma unroll
        for (int c = 0; c < 4; c++) {
            v8s bh = bhp[c * 4 + q];
            v8s bl = blp[c * 4 + q];
            acc = __builtin_amdgcn_mfma_f32_16x16x32_bf16(afh[c], bh, acc, 0, 0, 0);
            acc = __builtin_amdgcn_mfma_f32_16x16x32_bf16(afh[c], bl, acc, 0, 0, 0);
            acc = __builtin_amdgcn_mfma_f32_16x16x32_bf16(afl[c], bh, acc, 0, 0, 0);
        }
        #pragma unroll
        for (int r = 0; r < 4; r++) {
            int gr = rowbase + q * 4 + r;
            if (gr < NNODES) C[(size_t)gr * NF + n0 + m] = acc[r] * ds[r];
        }
    }
}

// ---- CSR aggregation: wave/node, pad8 rows, depth-16 gather pipeline ----
// Records prefetched 2 blocks ahead (recA/recB/recC rotation): block-B
// gathers are in flight while block-A drains -> ~16 outstanding gathers.
__global__ __launch_bounds__(256) void k_aggregate(
        const float* __restrict__ h, const float* __restrict__ dis,
        const int* __restrict__ rowptr, const int2* __restrict__ csr,
        const float* __restrict__ bias,
        unsigned short* __restrict__ yh, unsigned short* __restrict__ yl) {
    int n0 = (blockIdx.x * blockDim.x + threadIdx.x) >> 6;
    if (n0 >= NNODES) return;
    int n = __builtin_amdgcn_readfirstlane(n0);
    int lane = threadIdx.x & 63;
    const float2* hl = (const float2*)h + lane;        // row stride 64 float2
    float2 acc = hl[(size_t)n * 64];                   // self term (pre-scaled)
    int beg = rowptr[n], end = rowptr[n + 1];          // multiple of 8
    int len = end - beg;
    if (len >= 8) {
        int2 recA[8], recB[8];
        float2 vA[8], vB[8];
        #pragma unroll
        for (int j = 0; j < 8; j++) recA[j] = csr[beg + j];
        if (len >= 16) {
            int p = beg + 8;
            #pragma unroll
            for (int j = 0; j < 8; j++) recB[j] = csr[p + j];
            p += 8;
            #pragma unroll
            for (int j = 0; j < 8; j++) vA[j] = hl[(size_t)recA[j].x * 64];
            while (p < end) {
                int2 recC[8];
                #pragma unroll
                for (int j = 0; j < 8; j++) recC[j] = csr[p + j];
                #pragma unroll
                for (int j = 0; j < 8; j++) vB[j] = hl[(size_t)recB[j].x * 64];
                #pragma unroll
                for (int j = 0; j < 8; j++) {
                    float w = __int_as_float(recA[j].y);
                    acc.x += vA[j].x * w;
                    acc.y += vA[j].y * w;
                }
                #pragma unroll
                for (int j = 0; j < 8; j++) {
                    recA[j] = recB[j]; vA[j] = vB[j]; recB[j] = recC[j];
                }
                p += 8;
            }
            #pragma unroll
            for (int j = 0; j < 8; j++) vB[j] = hl[(size_t)recB[j].x * 64];
            #pragma unroll
            for (int j = 0; j < 8; j++) {
                float w = __int_as_float(recA[j].y);
                acc.x += vA[j].x * w;
                acc.y += vA[j].y * w;
            }
            #pragma unroll
            for (int j = 0; j < 8; j++) {
                float w = __int_as_float(recB[j].y);
                acc.x += vB[j].x * w;
                acc.y += vB[j].y * w;
            }
        } else {
            #pragma unroll
            for (int j = 0; j < 8; j++) vA[j] = hl[(size_t)recA[j].x * 64];
            #pragma unroll
            for (int j = 0; j < 8; j++) {
                float w = __int_as_float(recA[j].y);
                acc.x += vA[j].x * w;
                acc.y += vA[j].y * w;
            }
        }
    }
    float dn = dis[n];
    float2 b = ((const float2*)bias)[lane];
    float ox = fmaxf(acc.x * dn + b.x, 0.0f);
    float oy = fmaxf(acc.y * dn + b.y, 0.0f);
    ushort2 hh, ll;
    split_bf(ox, hh.x, ll.x);
    split_bf(oy, hh.y, ll.y);
    ((ushort2*)(yh + (size_t)n * NF))[lane] = hh;
    ((ushort2*)(yl + (size_t)n * NF))[lane] = ll;
}

// ---- GEMV from split input: h3[n] = dis[n] * dot(Zh+Zl, W3) -------------
__global__ void k_gemv128(const unsigned short* __restrict__ Zh,
                          const unsigned short* __restrict__ Zl,
                          const float* __restrict__ W3,
                          const float* __restrict__ dis, float* __restrict__ h3) {
    int n = (blockIdx.x * blockDim.x + threadIdx.x) >> 6;
    int lane = threadIdx.x & 63;
    if (n >= NNODES) return;
    ushort2 zh = ((const ushort2*)(Zh + (size_t)n * NF))[lane];
    ushort2 zl = ((const ushort2*)(Zl + (size_t)n * NF))[lane];
    float vx = bf2f(zh.x) + bf2f(zl.x);
    float vy = bf2f(zh.y) + bf2f(zl.y);
    float2 w = ((const float2*)W3)[lane];
    float s = vx * w.x + vy * w.y;
    for (int o = 32; o > 0; o >>= 1) s += __shfl_xor(s, o);
    if (lane == 0) h3[n] = s * dis[n];
}

// ---- scalar aggregation for output layer (padded rows) ------------------
__global__ void k_agg_scalar(const float* __restrict__ h3, const float* __restrict__ dis,
                             const int* __restrict__ rowptr, const int2* __restrict__ csr,
                             const float* __restrict__ b3, float* __restrict__ out) {
    int n = blockIdx.x * blockDim.x + threadIdx.x;
    if (n >= NNODES) return;
    float acc = h3[n];
    int beg = rowptr[n], end = rowptr[n + 1];
    for (int p = beg; p + 4 <= end; p += 4) {
        int2 e0 = csr[p], e1 = csr[p + 1], e2 = csr[p + 2], e3 = csr[p + 3];
        float v0 = h3[e0.x], v1 = h3[e1.x], v2 = h3[e2.x], v3 = h3[e3.x];
        acc += v0 * __int_as_float(e0.y) + v1 * __int_as_float(e1.y)
             + v2 * __int_as_float(e2.y) + v3 * __int_as_float(e3.y);
    }
    out[n] = acc * dis[n] + b3[0];
}

extern "C" void kernel_launch(void* const* d_in, const int* in_sizes, int n_in,
                              void* d_out, int out_size, void* d_ws, size_t ws_size,
                              hipStream_t stream) {
    const float* x  = (const float*)d_in[0];
    const int*   ei = (const int*)d_in[1];
    const float* ea = (const float*)d_in[2];
    const float* g  = (const float*)d_in[3];
    const float* be = (const float*)d_in[4];
    const float* W1 = (const float*)d_in[5];
    const float* b1 = (const float*)d_in[6];
    const float* W2 = (const float*)d_in[7];
    const float* b2 = (const float*)d_in[8];
    const float* W3 = (const float*)d_in[9];
    const float* b3 = (const float*)d_in[10];
    float* out = (float*)d_out;

    char* ws = (char*)d_ws;
    size_t off = 0;
    auto alloc = [&](size_t bytes) {
        void* p = ws + off;
        off += (bytes + 255) & ~((size_t)255);
        return p;
    };
    unsigned short* ah0 = (unsigned short*)alloc((size_t)NNODES * NF * 2);
    unsigned short* al0 = (unsigned short*)alloc((size_t)NNODES * NF * 2);
    unsigned short* ah1 = (unsigned short*)alloc((size_t)NNODES * NF * 2);
    unsigned short* al1 = (unsigned short*)alloc((size_t)NNODES * NF * 2);
    float* bufH   = (float*)alloc((size_t)NNODES * NF * 4);
    int*   rank   = (int*)  alloc((size_t)NEDGES * 4);
    float* dis    = (float*)alloc((size_t)NNODES * 4);
    int*   cnt    = (int*)  alloc((size_t)NNODES * 4);
    int*   rowptr = (int*)  alloc((size_t)(NNODES + 1) * 4);
    int2*  csr    = (int2*) alloc((size_t)CSR_CAP * 8);
    int*   bsum   = (int*)  alloc(256 * 4);
    float* h3     = (float*)alloc((size_t)NNODES * 4);
    unsigned short* Wh1T = (unsigned short*)alloc(128 * 128 * 2);
    unsigned short* Wl1T = (unsigned short*)alloc(128 * 128 * 2);
    unsigned short* Wh2T = (unsigned short*)alloc(128 * 128 * 2);
    unsigned short* Wl2T = (unsigned short*)alloc(128 * 128 * 2);
    (void)ws_size; (void)in_sizes; (void)n_in; (void)out_size;

    const int NB_N = (NNODES + 255) / 256;      // 196
    const int NB_E = (NEDGES + 255) / 256;      // 3125
    const int NB_W = (NNODES * 64 + 255) / 256; // 12500 (wave per node)
    const int NB_G = (NNODES + 63) / 64;        // 782  (gemm 64-row tiles)

    hipMemsetAsync(cnt, 0, (size_t)NNODES * 4, stream);
    k_count_rank<<<NB_E, 256, 0, stream>>>(ei, rank, cnt);
    k_scan1<<<NB_N, 256, 0, stream>>>(cnt, bsum);
    k_scan2<<<1, 256, 0, stream>>>(bsum, NB_N);
    k_scan3<<<NB_N, 256, 0, stream>>>(cnt, bsum, rowptr);
    k_scatter<<<NB_E, 256, 0, stream>>>(ei, ea, rank, rowptr, csr);
    k_prep<<<NB_N + 128, 256, 0, stream>>>(csr, csr, rowptr, cnt, dis,
                                           W1, W2, Wh1T, Wl1T, Wh2T, Wl2T, NB_N);

    k_layernorm<<<NB_W, 256, 0, stream>>>(x, g, be, ah0, al0);

    // layer 1
    k_gemm_mfma<<<NB_G, 256, 0, stream>>>(ah0, al0, Wh1T, Wl1T, dis, bufH);
    k_aggregate<<<NB_W, 256, 0, stream>>>(bufH, dis, rowptr, csr, b1, ah1, al1);
    // layer 2
    k_gemm_mfma<<<NB_G, 256, 0, stream>>>(ah1, al1, Wh2T, Wl2T, dis, bufH);
    k_aggregate<<<NB_W, 256, 0, stream>>>(bufH, dis, rowptr, csr, b2, ah0, al0);
    // layer 3
    k_gemv128<<<NB_W, 256, 0, stream>>>(ah0, al0, W3, dis, h3);
    k_agg_scalar<<<NB_N, 256, 0, stream>>>(h3, dis, rowptr, csr, b3, out);
}

// Round 7
// 308.027 us; speedup vs baseline: 1.3423x; 1.1842x over previous
//
#include <hip/hip_runtime.h>
#include <hip/hip_fp16.h>
#include <math.h>

#define NNODES 50000
#define NEDGES 800000
#define NF 128
#define CSR_CAP (NEDGES + 8 * NNODES)   // padded capacity (pad <= 7 per node)
constexpr float LN_EPS = 1e-5f;

typedef short v8s __attribute__((ext_vector_type(8)));
typedef unsigned short v8u __attribute__((ext_vector_type(8)));
typedef float v4f __attribute__((ext_vector_type(4)));

__device__ __forceinline__ float clean0(float v) {
    return (isnan(v) || isinf(v)) ? 0.0f : v;
}
__device__ __forceinline__ float cleanw(float v) {
    if (isnan(v)) return 0.0f;
    if (isinf(v)) return v > 0.0f ? 1.0f : 0.0f;
    return v;
}
__device__ __forceinline__ int clampN(int v) {
    return min(max(v, 0), NNODES - 1);
}
__device__ __forceinline__ int pad8(int v) { return (v + 7) & ~7; }

// bf16 helpers (RNE)
__device__ __forceinline__ unsigned short f2bf(float f) {
    unsigned int u = __float_as_uint(f);
    return (unsigned short)((u + 0x7FFFu + ((u >> 16) & 1u)) >> 16);
}
__device__ __forceinline__ float bf2f(unsigned short h) {
    return __uint_as_float(((unsigned int)h) << 16);
}
__device__ __forceinline__ void split_bf(float v, unsigned short& h, unsigned short& l) {
    h = f2bf(v);
    l = f2bf(v - bf2f(h));
}

// ---- pass 1: count in-degree, record per-edge rank (1 atomic/edge) ------
__global__ void k_count_rank(const int* __restrict__ ei, int* __restrict__ rank,
                             int* __restrict__ cnt) {
    int e = blockIdx.x * blockDim.x + threadIdx.x;
    if (e >= NEDGES) return;
    int c = clampN(ei[NEDGES + e]);
    rank[e] = atomicAdd(&cnt[c], 1);
}

// ---- 3-kernel exclusive scan of pad8(cnt) -> padded rowptr[N+1] ---------
__global__ void k_scan1(const int* __restrict__ cnt, int* __restrict__ bsum) {
    __shared__ int sm[256];
    int t = threadIdx.x;
    int i = blockIdx.x * 256 + t;
    sm[t] = (i < NNODES) ? pad8(cnt[i]) : 0;
    __syncthreads();
    for (int o = 128; o > 0; o >>= 1) {
        if (t < o) sm[t] += sm[t + o];
        __syncthreads();
    }
    if (t == 0) bsum[blockIdx.x] = sm[0];
}

__global__ void k_scan2(int* __restrict__ bsum, int nb) {
    __shared__ int sm[256];
    int t = threadIdx.x;
    int v = (t < nb) ? bsum[t] : 0;
    sm[t] = v;
    __syncthreads();
    for (int o = 1; o < 256; o <<= 1) {
        int add = (t >= o) ? sm[t - o] : 0;
        __syncthreads();
        sm[t] += add;
        __syncthreads();
    }
    if (t < nb) bsum[t] = sm[t] - v;   // exclusive
}

__global__ void k_scan3(const int* __restrict__ cnt, const int* __restrict__ bsum,
                        int* __restrict__ rowptr) {
    __shared__ int sm[256];
    int t = threadIdx.x;
    int i = blockIdx.x * 256 + t;
    int v = (i < NNODES) ? pad8(cnt[i]) : 0;
    sm[t] = v;
    __syncthreads();
    for (int o = 1; o < 256; o <<= 1) {
        int add = (t >= o) ? sm[t - o] : 0;
        __syncthreads();
        sm[t] += add;
        __syncthreads();
    }
    if (i < NNODES) rowptr[i + 1] = bsum[blockIdx.x] + sm[t];
    if (i == 0) rowptr[0] = 0;
}

// ---- pass 2: atomic-free scatter (src, cleaned w) -----------------------
__global__ void k_scatter(const int* __restrict__ ei, const float* __restrict__ ea,
                          const int* __restrict__ rank, const int* __restrict__ rowptr,
                          int2* __restrict__ csr) {
    int e = blockIdx.x * blockDim.x + threadIdx.x;
    if (e >= NEDGES) return;
    int r = clampN(ei[e]);
    int c = clampN(ei[NEDGES + e]);
    csr[rowptr[c] + rank[e]] = make_int2(r, __float_as_int(cleanw(ea[e])));
}

// ---- merged prep: deg/dis + explicit pad fill + weight split/transpose --
__global__ void k_prep(const int2* __restrict__ csrc, int2* __restrict__ csr,
                       const int* __restrict__ rowptr, const int* __restrict__ cnt,
                       float* __restrict__ dis,
                       const float* __restrict__ W1, const float* __restrict__ W2,
                       unsigned short* __restrict__ Wh1T, unsigned short* __restrict__ Wl1T,
                       unsigned short* __restrict__ Wh2T, unsigned short* __restrict__ Wl2T,
                       int nbn) {
    if ((int)blockIdx.x < nbn) {
        int n = blockIdx.x * 256 + threadIdx.x;
        if (n >= NNODES) return;
        int beg = rowptr[n];
        int c = cnt[n];
        float d = 1.0f;
        for (int p = beg; p < beg + c; p++) d += __int_as_float(csrc[p].y);
        for (int p = beg + c; p < beg + pad8(c); p++) csr[p] = make_int2(0, 0);
        dis[n] = (d > 0.0f) ? rsqrtf(d) : 0.0f;
    } else {
        int idx = (blockIdx.x - nbn) * 256 + threadIdx.x;   // [0, 32768)
        int m = idx >> 14;                                  // which matrix
        int n = (idx >> 7) & 127;
        int k = idx & 127;
        const float* W = m ? W2 : W1;
        unsigned short* Wh = m ? Wh2T : Wh1T;
        unsigned short* Wl = m ? Wl2T : Wl1T;
        unsigned short h, l;
        split_bf(W[k * 128 + n], h, l);
        Wh[n * 128 + k] = h;
        Wl[n * 128 + k] = l;
    }
}

// ---- LayerNorm: one wave per node; writes fp16 --------------------------
__global__ void k_layernorm(const float* __restrict__ x, const float* __restrict__ gamma,
                            const float* __restrict__ beta, unsigned short* __restrict__ z) {
    int n = (blockIdx.x * blockDim.x + threadIdx.x) >> 6;
    int lane = threadIdx.x & 63;
    if (n >= NNODES) return;
    float2 v = ((const float2*)(x + (size_t)n * NF))[lane];
    v.x = clean0(v.x); v.y = clean0(v.y);
    float s = v.x + v.y;
    for (int o = 32; o > 0; o >>= 1) s += __shfl_xor(s, o);
    float mu = s * (1.0f / NF);
    float dx = v.x - mu, dy = v.y - mu;
    float q = dx * dx + dy * dy;
    for (int o = 32; o > 0; o >>= 1) q += __shfl_xor(q, o);
    float rstd = rsqrtf(q * (1.0f / NF) + LN_EPS);
    float2 g = ((const float2*)gamma)[lane];
    float2 b = ((const float2*)beta)[lane];
    float ox = dx * rstd * g.x + b.x;
    float oy = dy * rstd * g.y + b.y;
    ((__half2*)z)[(size_t)n * 64 + lane] = __float22half2_rn(make_float2(ox, oy));
}

// ---- MFMA GEMM: C[r,:] = fp16( dis[r] * ((Ah+Al) @ (Wh+Wl)) ) -----------
// A input fp16; prologue splits exactly into bf16 hi+lo (fp16 = hi + lo).
__global__ __launch_bounds__(256) void k_gemm_mfma(
        const unsigned short* __restrict__ Ain,
        const unsigned short* __restrict__ BhT, const unsigned short* __restrict__ BlT,
        const float* __restrict__ dis, unsigned short* __restrict__ C) {
    int w = threadIdx.x >> 6;
    int lane = threadIdx.x & 63;
    int m = lane & 15;           // A row within tile / B,C col within tile
    int q = lane >> 4;           // quad
    int rowbase = blockIdx.x * 64 + w * 16;
    int arow = min(rowbase + m, NNODES - 1);

    const v8u* ap = (const v8u*)(Ain + (size_t)arow * NF);
    v8s afh[4], afl[4];
    #pragma unroll
    for (int c = 0; c < 4; c++) {
        v8u a = ap[c * 4 + q];
        #pragma unroll
        for (int j = 0; j < 8; j++) {
            float f = __half2float(__ushort_as_half(a[j]));
            unsigned short hh, ll;
            split_bf(f, hh, ll);
            afh[c][j] = (short)hh;
            afl[c][j] = (short)ll;
        }
    }

    float ds[4];
    #pragma unroll
    for (int r = 0; r < 4; r++) ds[r] = dis[min(rowbase + q * 4 + r, NNODES - 1)];

    for (int nt = 0; nt < 8; nt++) {
        int n0 = nt * 16;
        const v8s* bhp = (const v8s*)(BhT + (size_t)(n0 + m) * NF);
        const v8s* blp = (const v8s*)(BlT + (size_t)(n0 + m) * NF);
        v4f acc = {0.f, 0.f, 0.f, 0.f};
        #pragma unroll
        for (int c = 0; c < 4; c++) {
            v8s bh = bhp[c * 4 + q];
            v8s bl = blp[c * 4 + q];
            acc = __builtin_amdgcn_mfma_f32_16x16x32_bf16(afh[c], bh, acc, 0, 0, 0);
            acc = __builtin_amdgcn_mfma_f32_16x16x32_bf16(afh[c], bl, acc, 0, 0, 0);
            acc = __builtin_amdgcn_mfma_f32_16x16x32_bf16(afl[c], bh, acc, 0, 0, 0);
        }
        #pragma unroll
        for (int r = 0; r < 4; r++) {
            int gr = rowbase + q * 4 + r;
            if (gr < NNODES)
                C[(size_t)gr * NF + n0 + m] = __half_as_ushort(__float2half(acc[r] * ds[r]));
        }
    }
}

// ---- CSR aggregation: wave/node, pad8 rows, fp16 gathers (256B/row) -----
// h pre-scaled by dis[src]; y = fp16( relu(dis[n]*(h[n] + sum w*h[src]) + b) )
__global__ __launch_bounds__(256) void k_aggregate(
        const unsigned short* __restrict__ h, const float* __restrict__ dis,
        const int* __restrict__ rowptr, const int2* __restrict__ csr,
        const float* __restrict__ bias, unsigned short* __restrict__ y) {
    int n0 = (blockIdx.x * blockDim.x + threadIdx.x) >> 6;
    if (n0 >= NNODES) return;
    int n = __builtin_amdgcn_readfirstlane(n0);
    int lane = threadIdx.x & 63;
    const __half2* hp = (const __half2*)h;             // row stride 64 half2
    float2 acc = __half22float2(hp[(size_t)n * 64 + lane]);   // self term
    int beg = rowptr[n], end = rowptr[n + 1];          // multiple of 8
    int p = beg;
    if (p < end) {
        int2 rec[8];
        #pragma unroll
        for (int j = 0; j < 8; j++) rec[j] = csr[p + j];
        p += 8;
        while (p < end) {
            float2 v[8];
            #pragma unroll
            for (int j = 0; j < 8; j++) v[j] = __half22float2(hp[(size_t)rec[j].x * 64 + lane]);
            int2 rec2[8];
            #pragma unroll
            for (int j = 0; j < 8; j++) rec2[j] = csr[p + j];
            #pragma unroll
            for (int j = 0; j < 8; j++) {
                float w = __int_as_float(rec[j].y);
                acc.x += v[j].x * w;
                acc.y += v[j].y * w;
            }
            #pragma unroll
            for (int j = 0; j < 8; j++) rec[j] = rec2[j];
            p += 8;
        }
        float2 v[8];
        #pragma unroll
        for (int j = 0; j < 8; j++) v[j] = __half22float2(hp[(size_t)rec[j].x * 64 + lane]);
        #pragma unroll
        for (int j = 0; j < 8; j++) {
            float w = __int_as_float(rec[j].y);
            acc.x += v[j].x * w;
            acc.y += v[j].y * w;
        }
    }
    float dn = dis[n];
    float2 b = ((const float2*)bias)[lane];
    float ox = fmaxf(acc.x * dn + b.x, 0.0f);
    float oy = fmaxf(acc.y * dn + b.y, 0.0f);
    ((__half2*)y)[(size_t)n * 64 + lane] = __float22half2_rn(make_float2(ox, oy));
}

// ---- GEMV from fp16 input: h3[n] = dis[n] * dot(Z, W3) ------------------
__global__ void k_gemv128(const unsigned short* __restrict__ Z,
                          const float* __restrict__ W3,
                          const float* __restrict__ dis, float* __restrict__ h3) {
    int n = (blockIdx.x * blockDim.x + threadIdx.x) >> 6;
    int lane = threadIdx.x & 63;
    if (n >= NNODES) return;
    float2 v = __half22float2(((const __half2*)Z)[(size_t)n * 64 + lane]);
    float2 w = ((const float2*)W3)[lane];
    float s = v.x * w.x + v.y * w.y;
    for (int o = 32; o > 0; o >>= 1) s += __shfl_xor(s, o);
    if (lane == 0) h3[n] = s * dis[n];
}

// ---- scalar aggregation for output layer (padded rows) ------------------
__global__ void k_agg_scalar(const float* __restrict__ h3, const float* __restrict__ dis,
                             const int* __restrict__ rowptr, const int2* __restrict__ csr,
                             const float* __restrict__ b3, float* __restrict__ out) {
    int n = blockIdx.x * blockDim.x + threadIdx.x;
    if (n >= NNODES) return;
    float acc = h3[n];
    int beg = rowptr[n], end = rowptr[n + 1];
    for (int p = beg; p + 4 <= end; p += 4) {
        int2 e0 = csr[p], e1 = csr[p + 1], e2 = csr[p + 2], e3 = csr[p + 3];
        float v0 = h3[e0.x], v1 = h3[e1.x], v2 = h3[e2.x], v3 = h3[e3.x];
        acc += v0 * __int_as_float(e0.y) + v1 * __int_as_float(e1.y)
             + v2 * __int_as_float(e2.y) + v3 * __int_as_float(e3.y);
    }
    out[n] = acc * dis[n] + b3[0];
}

extern "C" void kernel_launch(void* const* d_in, const int* in_sizes, int n_in,
                              void* d_out, int out_size, void* d_ws, size_t ws_size,
                              hipStream_t stream) {
    const float* x  = (const float*)d_in[0];
    const int*   ei = (const int*)d_in[1];
    const float* ea = (const float*)d_in[2];
    const float* g  = (const float*)d_in[3];
    const float* be = (const float*)d_in[4];
    const float* W1 = (const float*)d_in[5];
    const float* b1 = (const float*)d_in[6];
    const float* W2 = (const float*)d_in[7];
    const float* b2 = (const float*)d_in[8];
    const float* W3 = (const float*)d_in[9];
    const float* b3 = (const float*)d_in[10];
    float* out = (float*)d_out;

    char* ws = (char*)d_ws;
    size_t off = 0;
    auto alloc = [&](size_t bytes) {
        void* p = ws + off;
        off += (bytes + 255) & ~((size_t)255);
        return p;
    };
    unsigned short* zbuf = (unsigned short*)alloc((size_t)NNODES * NF * 2);
    unsigned short* hbuf = (unsigned short*)alloc((size_t)NNODES * NF * 2);
    int*   rank   = (int*)  alloc((size_t)NEDGES * 4);
    float* dis    = (float*)alloc((size_t)NNODES * 4);
    int*   cnt    = (int*)  alloc((size_t)NNODES * 4);
    int*   rowptr = (int*)  alloc((size_t)(NNODES + 1) * 4);
    int2*  csr    = (int2*) alloc((size_t)CSR_CAP * 8);
    int*   bsum   = (int*)  alloc(256 * 4);
    float* h3     = (float*)alloc((size_t)NNODES * 4);
    unsigned short* Wh1T = (unsigned short*)alloc(128 * 128 * 2);
    unsigned short* Wl1T = (unsigned short*)alloc(128 * 128 * 2);
    unsigned short* Wh2T = (unsigned short*)alloc(128 * 128 * 2);
    unsigned short* Wl2T = (unsigned short*)alloc(128 * 128 * 2);
    (void)ws_size; (void)in_sizes; (void)n_in; (void)out_size;

    const int NB_N = (NNODES + 255) / 256;      // 196
    const int NB_E = (NEDGES + 255) / 256;      // 3125
    const int NB_W = (NNODES * 64 + 255) / 256; // 12500 (wave per node)
    const int NB_G = (NNODES + 63) / 64;        // 782  (gemm 64-row tiles)

    hipMemsetAsync(cnt, 0, (size_t)NNODES * 4, stream);
    k_count_rank<<<NB_E, 256, 0, stream>>>(ei, rank, cnt);
    k_scan1<<<NB_N, 256, 0, stream>>>(cnt, bsum);
    k_scan2<<<1, 256, 0, stream>>>(bsum, NB_N);
    k_scan3<<<NB_N, 256, 0, stream>>>(cnt, bsum, rowptr);
    k_scatter<<<NB_E, 256, 0, stream>>>(ei, ea, rank, rowptr, csr);
    k_prep<<<NB_N + 128, 256, 0, stream>>>(csr, csr, rowptr, cnt, dis,
                                           W1, W2, Wh1T, Wl1T, Wh2T, Wl2T, NB_N);

    k_layernorm<<<NB_W, 256, 0, stream>>>(x, g, be, zbuf);

    // layer 1
    k_gemm_mfma<<<NB_G, 256, 0, stream>>>(zbuf, Wh1T, Wl1T, dis, hbuf);
    k_aggregate<<<NB_W, 256, 0, stream>>>(hbuf, dis, rowptr, csr, b1, zbuf);
    // layer 2
    k_gemm_mfma<<<NB_G, 256, 0, stream>>>(zbuf, Wh2T, Wl2T, dis, hbuf);
    k_aggregate<<<NB_W, 256, 0, stream>>>(hbuf, dis, rowptr, csr, b2, zbuf);
    // layer 3
    k_gemv128<<<NB_W, 256, 0, stream>>>(zbuf, W3, dis, h3);
    k_agg_scalar<<<NB_N, 256, 0, stream>>>(h3, dis, rowptr, csr, b3, out);
}

// Round 8
// 303.613 us; speedup vs baseline: 1.3618x; 1.0145x over previous
//
#include <hip/hip_runtime.h>
#include <hip/hip_fp16.h>
#include <math.h>

#define NNODES 50000
#define NEDGES 800000
#define NF 128
#define BK 64                    // bucket slots per node (P(deg>=64) ~ 1e-18)
constexpr float LN_EPS = 1e-5f;

typedef short v8s __attribute__((ext_vector_type(8)));
typedef unsigned short v8u __attribute__((ext_vector_type(8)));
typedef float v4f __attribute__((ext_vector_type(4)));

__device__ __forceinline__ float clean0(float v) {
    return (isnan(v) || isinf(v)) ? 0.0f : v;
}
__device__ __forceinline__ float cleanw(float v) {
    if (isnan(v)) return 0.0f;
    if (isinf(v)) return v > 0.0f ? 1.0f : 0.0f;
    return v;
}
__device__ __forceinline__ int clampN(int v) {
    return min(max(v, 0), NNODES - 1);
}
__device__ __forceinline__ int pad8(int v) { return (v + 7) & ~7; }

// bf16 helpers (RNE)
__device__ __forceinline__ unsigned short f2bf(float f) {
    unsigned int u = __float_as_uint(f);
    return (unsigned short)((u + 0x7FFFu + ((u >> 16) & 1u)) >> 16);
}
__device__ __forceinline__ float bf2f(unsigned short h) {
    return __uint_as_float(((unsigned int)h) << 16);
}
__device__ __forceinline__ void split_bf(float v, unsigned short& h, unsigned short& l) {
    h = f2bf(v);
    l = f2bf(v - bf2f(h));
}

// ---- one-pass bucket CSR build: 1 atomic + 1 random 8B store per edge ---
__global__ void k_build(const int* __restrict__ ei, const float* __restrict__ ea,
                        int* __restrict__ cnt, int2* __restrict__ bucket) {
    int e = blockIdx.x * blockDim.x + threadIdx.x;
    if (e >= NEDGES) return;
    int r = clampN(ei[e]);
    int c = clampN(ei[NEDGES + e]);
    float w = cleanw(ea[e]);
    int pos = atomicAdd(&cnt[c], 1);
    if (pos < BK) bucket[(c << 6) + pos] = make_int2(r, __float_as_int(w));
}

// ---- merged prep: deg/dis + pad fill + cnt->pad8 + weight split ---------
// blocks [0, nbn): per-node. blocks [nbn, nbn+128): W1/W2 bf16 split, [n][k].
__global__ void k_prep(int2* __restrict__ bucket, int* __restrict__ cnt,
                       float* __restrict__ dis,
                       const float* __restrict__ W1, const float* __restrict__ W2,
                       unsigned short* __restrict__ Wh1T, unsigned short* __restrict__ Wl1T,
                       unsigned short* __restrict__ Wh2T, unsigned short* __restrict__ Wl2T,
                       int nbn) {
    if ((int)blockIdx.x < nbn) {
        int n = blockIdx.x * 256 + threadIdx.x;
        if (n >= NNODES) return;
        int c = min(cnt[n], BK);
        int beg = n << 6;
        float d = 1.0f;
        for (int p = beg; p < beg + c; p++) d += __int_as_float(bucket[p].y);
        for (int p = beg + c; p < beg + pad8(c); p++) bucket[p] = make_int2(0, 0);
        dis[n] = (d > 0.0f) ? rsqrtf(d) : 0.0f;
        cnt[n] = pad8(c);                      // aggregate reads padded length
    } else {
        int idx = (blockIdx.x - nbn) * 256 + threadIdx.x;   // [0, 32768)
        int m = idx >> 14;                                  // which matrix
        int n = (idx >> 7) & 127;
        int k = idx & 127;
        const float* W = m ? W2 : W1;
        unsigned short* Wh = m ? Wh2T : Wh1T;
        unsigned short* Wl = m ? Wl2T : Wl1T;
        unsigned short h, l;
        split_bf(W[k * 128 + n], h, l);
        Wh[n * 128 + k] = h;
        Wl[n * 128 + k] = l;
    }
}

// ---- LayerNorm: one wave per node; writes fp16 --------------------------
__global__ void k_layernorm(const float* __restrict__ x, const float* __restrict__ gamma,
                            const float* __restrict__ beta, unsigned short* __restrict__ z) {
    int n = (blockIdx.x * blockDim.x + threadIdx.x) >> 6;
    int lane = threadIdx.x & 63;
    if (n >= NNODES) return;
    float2 v = ((const float2*)(x + (size_t)n * NF))[lane];
    v.x = clean0(v.x); v.y = clean0(v.y);
    float s = v.x + v.y;
    for (int o = 32; o > 0; o >>= 1) s += __shfl_xor(s, o);
    float mu = s * (1.0f / NF);
    float dx = v.x - mu, dy = v.y - mu;
    float q = dx * dx + dy * dy;
    for (int o = 32; o > 0; o >>= 1) q += __shfl_xor(q, o);
    float rstd = rsqrtf(q * (1.0f / NF) + LN_EPS);
    float2 g = ((const float2*)gamma)[lane];
    float2 b = ((const float2*)beta)[lane];
    float ox = dx * rstd * g.x + b.x;
    float oy = dy * rstd * g.y + b.y;
    ((__half2*)z)[(size_t)n * 64 + lane] = __float22half2_rn(make_float2(ox, oy));
}

// ---- MFMA GEMM: C[r,:] = fp16( dis[r] * ((Ah+Al) @ (Wh+Wl)) ) -----------
// A input fp16; prologue splits exactly into bf16 hi+lo (fp16 = hi + lo).
__global__ __launch_bounds__(256) void k_gemm_mfma(
        const unsigned short* __restrict__ Ain,
        const unsigned short* __restrict__ BhT, const unsigned short* __restrict__ BlT,
        const float* __restrict__ dis, unsigned short* __restrict__ C) {
    int w = threadIdx.x >> 6;
    int lane = threadIdx.x & 63;
    int m = lane & 15;           // A row within tile / B,C col within tile
    int q = lane >> 4;           // quad
    int rowbase = blockIdx.x * 64 + w * 16;
    int arow = min(rowbase + m, NNODES - 1);

    const v8u* ap = (const v8u*)(Ain + (size_t)arow * NF);
    v8s afh[4], afl[4];
    #pragma unroll
    for (int c = 0; c < 4; c++) {
        v8u a = ap[c * 4 + q];
        #pragma unroll
        for (int j = 0; j < 8; j++) {
            float f = __half2float(__ushort_as_half(a[j]));
            unsigned short hh, ll;
            split_bf(f, hh, ll);
            afh[c][j] = (short)hh;
            afl[c][j] = (short)ll;
        }
    }

    float ds[4];
    #pragma unroll
    for (int r = 0; r < 4; r++) ds[r] = dis[min(rowbase + q * 4 + r, NNODES - 1)];

    for (int nt = 0; nt < 8; nt++) {
        int n0 = nt * 16;
        const v8s* bhp = (const v8s*)(BhT + (size_t)(n0 + m) * NF);
        const v8s* blp = (const v8s*)(BlT + (size_t)(n0 + m) * NF);
        v4f acc = {0.f, 0.f, 0.f, 0.f};
        #pragma unroll
        for (int c = 0; c < 4; c++) {
            v8s bh = bhp[c * 4 + q];
            v8s bl = blp[c * 4 + q];
            acc = __builtin_amdgcn_mfma_f32_16x16x32_bf16(afh[c], bh, acc, 0, 0, 0);
            acc = __builtin_amdgcn_mfma_f32_16x16x32_bf16(afh[c], bl, acc, 0, 0, 0);
            acc = __builtin_amdgcn_mfma_f32_16x16x32_bf16(afl[c], bh, acc, 0, 0, 0);
        }
        #pragma unroll
        for (int r = 0; r < 4; r++) {
            int gr = rowbase + q * 4 + r;
            if (gr < NNODES)
                C[(size_t)gr * NF + n0 + m] = __half_as_ushort(__float2half(acc[r] * ds[r]));
        }
    }
}

// ---- bucket aggregation: wave/node, fp16 gathers (256B/row) -------------
// h pre-scaled by dis[src]; y = fp16( relu(dis[n]*(h[n] + sum w*h[src]) + b) )
__global__ __launch_bounds__(256) void k_aggregate(
        const unsigned short* __restrict__ h, const float* __restrict__ dis,
        const int* __restrict__ cnt, const int2* __restrict__ bucket,
        const float* __restrict__ bias, unsigned short* __restrict__ y) {
    int n0 = (blockIdx.x * blockDim.x + threadIdx.x) >> 6;
    if (n0 >= NNODES) return;
    int n = __builtin_amdgcn_readfirstlane(n0);
    int lane = threadIdx.x & 63;
    const __half2* hp = (const __half2*)h;             // row stride 64 half2
    float2 acc = __half22float2(hp[(size_t)n * 64 + lane]);   // self term
    int beg = n << 6;
    int end = beg + cnt[n];                            // padded length, mult of 8
    int p = beg;
    if (p < end) {
        int2 rec[8];
        #pragma unroll
        for (int j = 0; j < 8; j++) rec[j] = bucket[p + j];
        p += 8;
        while (p < end) {
            float2 v[8];
            #pragma unroll
            for (int j = 0; j < 8; j++) v[j] = __half22float2(hp[(size_t)rec[j].x * 64 + lane]);
            int2 rec2[8];
            #pragma unroll
            for (int j = 0; j < 8; j++) rec2[j] = bucket[p + j];
            #pragma unroll
            for (int j = 0; j < 8; j++) {
                float w = __int_as_float(rec[j].y);
                acc.x += v[j].x * w;
                acc.y += v[j].y * w;
            }
            #pragma unroll
            for (int j = 0; j < 8; j++) rec[j] = rec2[j];
            p += 8;
        }
        float2 v[8];
        #pragma unroll
        for (int j = 0; j < 8; j++) v[j] = __half22float2(hp[(size_t)rec[j].x * 64 + lane]);
        #pragma unroll
        for (int j = 0; j < 8; j++) {
            float w = __int_as_float(rec[j].y);
            acc.x += v[j].x * w;
            acc.y += v[j].y * w;
        }
    }
    float dn = dis[n];
    float2 b = ((const float2*)bias)[lane];
    float ox = fmaxf(acc.x * dn + b.x, 0.0f);
    float oy = fmaxf(acc.y * dn + b.y, 0.0f);
    ((__half2*)y)[(size_t)n * 64 + lane] = __float22half2_rn(make_float2(ox, oy));
}

// ---- GEMV from fp16 input: h3[n] = dis[n] * dot(Z, W3) ------------------
__global__ void k_gemv128(const unsigned short* __restrict__ Z,
                          const float* __restrict__ W3,
                          const float* __restrict__ dis, float* __restrict__ h3) {
    int n = (blockIdx.x * blockDim.x + threadIdx.x) >> 6;
    int lane = threadIdx.x & 63;
    if (n >= NNODES) return;
    float2 v = __half22float2(((const __half2*)Z)[(size_t)n * 64 + lane]);
    float2 w = ((const float2*)W3)[lane];
    float s = v.x * w.x + v.y * w.y;
    for (int o = 32; o > 0; o >>= 1) s += __shfl_xor(s, o);
    if (lane == 0) h3[n] = s * dis[n];
}

// ---- scalar aggregation for output layer (padded buckets) ---------------
__global__ void k_agg_scalar(const float* __restrict__ h3, const float* __restrict__ dis,
                             const int* __restrict__ cnt, const int2* __restrict__ bucket,
                             const float* __restrict__ b3, float* __restrict__ out) {
    int n = blockIdx.x * blockDim.x + threadIdx.x;
    if (n >= NNODES) return;
    float acc = h3[n];
    int beg = n << 6;
    int end = beg + cnt[n];
    for (int p = beg; p + 4 <= end; p += 4) {
        int2 e0 = bucket[p], e1 = bucket[p + 1], e2 = bucket[p + 2], e3 = bucket[p + 3];
        float v0 = h3[e0.x], v1 = h3[e1.x], v2 = h3[e2.x], v3 = h3[e3.x];
        acc += v0 * __int_as_float(e0.y) + v1 * __int_as_float(e1.y)
             + v2 * __int_as_float(e2.y) + v3 * __int_as_float(e3.y);
    }
    out[n] = acc * dis[n] + b3[0];
}

extern "C" void kernel_launch(void* const* d_in, const int* in_sizes, int n_in,
                              void* d_out, int out_size, void* d_ws, size_t ws_size,
                              hipStream_t stream) {
    const float* x  = (const float*)d_in[0];
    const int*   ei = (const int*)d_in[1];
    const float* ea = (const float*)d_in[2];
    const float* g  = (const float*)d_in[3];
    const float* be = (const float*)d_in[4];
    const float* W1 = (const float*)d_in[5];
    const float* b1 = (const float*)d_in[6];
    const float* W2 = (const float*)d_in[7];
    const float* b2 = (const float*)d_in[8];
    const float* W3 = (const float*)d_in[9];
    const float* b3 = (const float*)d_in[10];
    float* out = (float*)d_out;

    char* ws = (char*)d_ws;
    size_t off = 0;
    auto alloc = [&](size_t bytes) {
        void* p = ws + off;
        off += (bytes + 255) & ~((size_t)255);
        return p;
    };
    unsigned short* zbuf = (unsigned short*)alloc((size_t)NNODES * NF * 2);
    unsigned short* hbuf = (unsigned short*)alloc((size_t)NNODES * NF * 2);
    float* dis    = (float*)alloc((size_t)NNODES * 4);
    int*   cnt    = (int*)  alloc((size_t)NNODES * 4);
    int2*  bucket = (int2*) alloc((size_t)NNODES * BK * 8);
    float* h3     = (float*)alloc((size_t)NNODES * 4);
    unsigned short* Wh1T = (unsigned short*)alloc(128 * 128 * 2);
    unsigned short* Wl1T = (unsigned short*)alloc(128 * 128 * 2);
    unsigned short* Wh2T = (unsigned short*)alloc(128 * 128 * 2);
    unsigned short* Wl2T = (unsigned short*)alloc(128 * 128 * 2);
    (void)ws_size; (void)in_sizes; (void)n_in; (void)out_size;

    const int NB_N = (NNODES + 255) / 256;      // 196
    const int NB_E = (NEDGES + 255) / 256;      // 3125
    const int NB_W = (NNODES * 64 + 255) / 256; // 12500 (wave per node)
    const int NB_G = (NNODES + 63) / 64;        // 782  (gemm 64-row tiles)

    hipMemsetAsync(cnt, 0, (size_t)NNODES * 4, stream);
    k_build<<<NB_E, 256, 0, stream>>>(ei, ea, cnt, bucket);
    k_prep<<<NB_N + 128, 256, 0, stream>>>(bucket, cnt, dis,
                                           W1, W2, Wh1T, Wl1T, Wh2T, Wl2T, NB_N);

    k_layernorm<<<NB_W, 256, 0, stream>>>(x, g, be, zbuf);

    // layer 1
    k_gemm_mfma<<<NB_G, 256, 0, stream>>>(zbuf, Wh1T, Wl1T, dis, hbuf);
    k_aggregate<<<NB_W, 256, 0, stream>>>(hbuf, dis, cnt, bucket, b1, zbuf);
    // layer 2
    k_gemm_mfma<<<NB_G, 256, 0, stream>>>(zbuf, Wh2T, Wl2T, dis, hbuf);
    k_aggregate<<<NB_W, 256, 0, stream>>>(hbuf, dis, cnt, bucket, b2, zbuf);
    // layer 3
    k_gemv128<<<NB_W, 256, 0, stream>>>(zbuf, W3, dis, h3);
    k_agg_scalar<<<NB_N, 256, 0, stream>>>(h3, dis, cnt, bucket, b3, out);
}

// Round 9
// 296.234 us; speedup vs baseline: 1.3957x; 1.0249x over previous
//
#include <hip/hip_runtime.h>
#include <hip/hip_fp16.h>
#include <math.h>

#define NNODES 50000
#define NEDGES 800000
#define NF 128
#define BK 128                   // bucket slots per node (4 shards x 32)
constexpr float LN_EPS = 1e-5f;

typedef short v8s __attribute__((ext_vector_type(8)));
typedef unsigned short v8u __attribute__((ext_vector_type(8)));
typedef float v4f __attribute__((ext_vector_type(4)));

__device__ __forceinline__ float clean0(float v) {
    return (isnan(v) || isinf(v)) ? 0.0f : v;
}
__device__ __forceinline__ float cleanw(float v) {
    if (isnan(v)) return 0.0f;
    if (isinf(v)) return v > 0.0f ? 1.0f : 0.0f;
    return v;
}
__device__ __forceinline__ int clampN(int v) {
    return min(max(v, 0), NNODES - 1);
}
__device__ __forceinline__ int pad8(int v) { return (v + 7) & ~7; }

// bf16 helpers (RNE)
__device__ __forceinline__ unsigned short f2bf(float f) {
    unsigned int u = __float_as_uint(f);
    return (unsigned short)((u + 0x7FFFu + ((u >> 16) & 1u)) >> 16);
}
__device__ __forceinline__ float bf2f(unsigned short h) {
    return __uint_as_float(((unsigned int)h) << 16);
}
__device__ __forceinline__ void split_bf(float v, unsigned short& h, unsigned short& l) {
    h = f2bf(v);
    l = f2bf(v - bf2f(h));
}

// ---- kernel A: sharded bucket build (blocks < nbb) UNION layernorm ------
// build: shard = e&3 -> 4x less same-address atomic contention.
// layernorm: independent of the graph; fills build's latency-bound tail.
__global__ void k_build_ln(const int* __restrict__ ei, const float* __restrict__ ea,
                           int* __restrict__ cnt4, int2* __restrict__ bucket,
                           const float* __restrict__ x, const float* __restrict__ gamma,
                           const float* __restrict__ beta, unsigned short* __restrict__ z,
                           int nbb) {
    if ((int)blockIdx.x < nbb) {
        int e = blockIdx.x * 256 + threadIdx.x;
        if (e >= NEDGES) return;
        int r = clampN(ei[e]);
        int c = clampN(ei[NEDGES + e]);
        float w = cleanw(ea[e]);
        int s = e & 3;
        int pos = atomicAdd(&cnt4[(c << 2) + s], 1);
        if (pos < 32) bucket[(c << 7) + (s << 5) + pos] = make_int2(r, __float_as_int(w));
    } else {
        int bid = blockIdx.x - nbb;
        int n = (bid * 256 + threadIdx.x) >> 6;
        int lane = threadIdx.x & 63;
        if (n >= NNODES) return;
        float2 v = ((const float2*)(x + (size_t)n * NF))[lane];
        v.x = clean0(v.x); v.y = clean0(v.y);
        float s = v.x + v.y;
        for (int o = 32; o > 0; o >>= 1) s += __shfl_xor(s, o);
        float mu = s * (1.0f / NF);
        float dx = v.x - mu, dy = v.y - mu;
        float q = dx * dx + dy * dy;
        for (int o = 32; o > 0; o >>= 1) q += __shfl_xor(q, o);
        float rstd = rsqrtf(q * (1.0f / NF) + LN_EPS);
        float2 g = ((const float2*)gamma)[lane];
        float2 b = ((const float2*)beta)[lane];
        float ox = dx * rstd * g.x + b.x;
        float oy = dy * rstd * g.y + b.y;
        ((__half2*)z)[(size_t)n * 64 + lane] = __float22half2_rn(make_float2(ox, oy));
    }
}

// ---- kernel B: prep. blocks < nbn: per-node shard compaction + deg/dis +
// pad fill + padded count. blocks >= nbn: W1/W2 bf16 split transposed.
__global__ void k_prep(int2* __restrict__ bucket, const int* __restrict__ cnt4,
                       int* __restrict__ cntp, float* __restrict__ dis,
                       const float* __restrict__ W1, const float* __restrict__ W2,
                       unsigned short* __restrict__ Wh1T, unsigned short* __restrict__ Wl1T,
                       unsigned short* __restrict__ Wh2T, unsigned short* __restrict__ Wl2T,
                       int nbn) {
    if ((int)blockIdx.x < nbn) {
        int n = blockIdx.x * 256 + threadIdx.x;
        if (n >= NNODES) return;
        int4 c4 = ((const int4*)cnt4)[n];
        int cs[4] = { min(c4.x, 32), min(c4.y, 32), min(c4.z, 32), min(c4.w, 32) };
        int base = n << 7;
        float d = 1.0f;
        // shard 0 stays in place
        for (int i = 0; i < cs[0]; i++) d += __int_as_float(bucket[base + i].y);
        int total = cs[0];
        // shards 1..3: compact forward (dst <= src always)
        #pragma unroll
        for (int s = 1; s < 4; s++) {
            int src = base + (s << 5);
            for (int i = 0; i < cs[s]; i++) {
                int2 rec = bucket[src + i];
                d += __int_as_float(rec.y);
                bucket[base + total + i] = rec;
            }
            total += cs[s];
        }
        for (int p = total; p < pad8(total); p++) bucket[base + p] = make_int2(0, 0);
        dis[n] = rsqrtf(d);                    // d >= 1 always
        cntp[n] = pad8(total);
    } else {
        int idx = (blockIdx.x - nbn) * 256 + threadIdx.x;   // [0, 32768)
        int m = idx >> 14;                                  // which matrix
        int n = (idx >> 7) & 127;
        int k = idx & 127;
        const float* W = m ? W2 : W1;
        unsigned short* Wh = m ? Wh2T : Wh1T;
        unsigned short* Wl = m ? Wl2T : Wl1T;
        unsigned short h, l;
        split_bf(W[k * 128 + n], h, l);
        Wh[n * 128 + k] = h;
        Wl[n * 128 + k] = l;
    }
}

// ---- MFMA GEMM: C[r,:] = fp16( dis[r] * ((Ah+Al) @ (Wh+Wl)) ) -----------
// A input fp16; prologue splits exactly into bf16 hi+lo (fp16 = hi + lo).
__global__ __launch_bounds__(256) void k_gemm_mfma(
        const unsigned short* __restrict__ Ain,
        const unsigned short* __restrict__ BhT, const unsigned short* __restrict__ BlT,
        const float* __restrict__ dis, unsigned short* __restrict__ C) {
    int w = threadIdx.x >> 6;
    int lane = threadIdx.x & 63;
    int m = lane & 15;           // A row within tile / B,C col within tile
    int q = lane >> 4;           // quad
    int rowbase = blockIdx.x * 64 + w * 16;
    int arow = min(rowbase + m, NNODES - 1);

    const v8u* ap = (const v8u*)(Ain + (size_t)arow * NF);
    v8s afh[4], afl[4];
    #pragma unroll
    for (int c = 0; c < 4; c++) {
        v8u a = ap[c * 4 + q];
        #pragma unroll
        for (int j = 0; j < 8; j++) {
            float f = __half2float(__ushort_as_half(a[j]));
            unsigned short hh, ll;
            split_bf(f, hh, ll);
            afh[c][j] = (short)hh;
            afl[c][j] = (short)ll;
        }
    }

    float ds[4];
    #pragma unroll
    for (int r = 0; r < 4; r++) ds[r] = dis[min(rowbase + q * 4 + r, NNODES - 1)];

    for (int nt = 0; nt < 8; nt++) {
        int n0 = nt * 16;
        const v8s* bhp = (const v8s*)(BhT + (size_t)(n0 + m) * NF);
        const v8s* blp = (const v8s*)(BlT + (size_t)(n0 + m) * NF);
        v4f acc = {0.f, 0.f, 0.f, 0.f};
        #pragma unroll
        for (int c = 0; c < 4; c++) {
            v8s bh = bhp[c * 4 + q];
            v8s bl = blp[c * 4 + q];
            acc = __builtin_amdgcn_mfma_f32_16x16x32_bf16(afh[c], bh, acc, 0, 0, 0);
            acc = __builtin_amdgcn_mfma_f32_16x16x32_bf16(afh[c], bl, acc, 0, 0, 0);
            acc = __builtin_amdgcn_mfma_f32_16x16x32_bf16(afl[c], bh, acc, 0, 0, 0);
        }
        #pragma unroll
        for (int r = 0; r < 4; r++) {
            int gr = rowbase + q * 4 + r;
            if (gr < NNODES)
                C[(size_t)gr * NF + n0 + m] = __half_as_ushort(__float2half(acc[r] * ds[r]));
        }
    }
}

// ---- bucket aggregation: wave/node, fp16 gathers (256B/row) -------------
// h pre-scaled by dis[src]. LAST=false: y = fp16(relu(dis_n*acc + b)).
// LAST=true: fused output GEMV — h3[n] = dis3[n] * dot(relu(...), W3).
template <bool LAST>
__global__ __launch_bounds__(256) void k_aggregate(
        const unsigned short* __restrict__ h, const float* __restrict__ dis,
        const int* __restrict__ cntp, const int2* __restrict__ bucket,
        const float* __restrict__ bias, unsigned short* __restrict__ y,
        const float* __restrict__ W3, float* __restrict__ h3) {
    int n0 = (blockIdx.x * blockDim.x + threadIdx.x) >> 6;
    if (n0 >= NNODES) return;
    int n = __builtin_amdgcn_readfirstlane(n0);
    int lane = threadIdx.x & 63;
    const __half2* hp = (const __half2*)h;             // row stride 64 half2
    float2 acc = __half22float2(hp[(size_t)n * 64 + lane]);   // self term
    int beg = n << 7;
    int end = beg + cntp[n];                           // padded, mult of 8
    int p = beg;
    if (p < end) {
        int2 rec[8];
        #pragma unroll
        for (int j = 0; j < 8; j++) rec[j] = bucket[p + j];
        p += 8;
        while (p < end) {
            float2 v[8];
            #pragma unroll
            for (int j = 0; j < 8; j++) v[j] = __half22float2(hp[(size_t)rec[j].x * 64 + lane]);
            int2 rec2[8];
            #pragma unroll
            for (int j = 0; j < 8; j++) rec2[j] = bucket[p + j];
            #pragma unroll
            for (int j = 0; j < 8; j++) {
                float w = __int_as_float(rec[j].y);
                acc.x += v[j].x * w;
                acc.y += v[j].y * w;
            }
            #pragma unroll
            for (int j = 0; j < 8; j++) rec[j] = rec2[j];
            p += 8;
        }
        float2 v[8];
        #pragma unroll
        for (int j = 0; j < 8; j++) v[j] = __half22float2(hp[(size_t)rec[j].x * 64 + lane]);
        #pragma unroll
        for (int j = 0; j < 8; j++) {
            float w = __int_as_float(rec[j].y);
            acc.x += v[j].x * w;
            acc.y += v[j].y * w;
        }
    }
    float dn = dis[n];
    float2 b = ((const float2*)bias)[lane];
    float ox = fmaxf(acc.x * dn + b.x, 0.0f);
    float oy = fmaxf(acc.y * dn + b.y, 0.0f);
    if (LAST) {
        float2 w3 = ((const float2*)W3)[lane];
        float s = ox * w3.x + oy * w3.y;
        for (int o = 32; o > 0; o >>= 1) s += __shfl_xor(s, o);
        if (lane == 0) h3[n] = s * dn;   // wait: needs dis[n] of OUTPUT layer
    } else {
        ((__half2*)y)[(size_t)n * 64 + lane] = __float22half2_rn(make_float2(ox, oy));
    }
}

// ---- scalar aggregation for output layer (padded buckets) ---------------
__global__ void k_agg_scalar(const float* __restrict__ h3, const float* __restrict__ dis,
                             const int* __restrict__ cntp, const int2* __restrict__ bucket,
                             const float* __restrict__ b3, float* __restrict__ out) {
    int n = blockIdx.x * blockDim.x + threadIdx.x;
    if (n >= NNODES) return;
    float acc = h3[n];
    int beg = n << 7;
    int end = beg + cntp[n];
    for (int p = beg; p + 4 <= end; p += 4) {
        int2 e0 = bucket[p], e1 = bucket[p + 1], e2 = bucket[p + 2], e3 = bucket[p + 3];
        float v0 = h3[e0.x], v1 = h3[e1.x], v2 = h3[e2.x], v3 = h3[e3.x];
        acc += v0 * __int_as_float(e0.y) + v1 * __int_as_float(e1.y)
             + v2 * __int_as_float(e2.y) + v3 * __int_as_float(e3.y);
    }
    out[n] = acc * dis[n] + b3[0];
}

extern "C" void kernel_launch(void* const* d_in, const int* in_sizes, int n_in,
                              void* d_out, int out_size, void* d_ws, size_t ws_size,
                              hipStream_t stream) {
    const float* x  = (const float*)d_in[0];
    const int*   ei = (const int*)d_in[1];
    const float* ea = (const float*)d_in[2];
    const float* g  = (const float*)d_in[3];
    const float* be = (const float*)d_in[4];
    const float* W1 = (const float*)d_in[5];
    const float* b1 = (const float*)d_in[6];
    const float* W2 = (const float*)d_in[7];
    const float* b2 = (const float*)d_in[8];
    const float* W3 = (const float*)d_in[9];
    const float* b3 = (const float*)d_in[10];
    float* out = (float*)d_out;

    char* ws = (char*)d_ws;
    size_t off = 0;
    auto alloc = [&](size_t bytes) {
        void* p = ws + off;
        off += (bytes + 255) & ~((size_t)255);
        return p;
    };
    unsigned short* zbuf = (unsigned short*)alloc((size_t)NNODES * NF * 2);
    unsigned short* hbuf = (unsigned short*)alloc((size_t)NNODES * NF * 2);
    float* dis    = (float*)alloc((size_t)NNODES * 4);
    int*   cnt4   = (int*)  alloc((size_t)NNODES * 4 * 4);
    int*   cntp   = (int*)  alloc((size_t)NNODES * 4);
    int2*  bucket = (int2*) alloc((size_t)NNODES * BK * 8);
    float* h3     = (float*)alloc((size_t)NNODES * 4);
    unsigned short* Wh1T = (unsigned short*)alloc(128 * 128 * 2);
    unsigned short* Wl1T = (unsigned short*)alloc(128 * 128 * 2);
    unsigned short* Wh2T = (unsigned short*)alloc(128 * 128 * 2);
    unsigned short* Wl2T = (unsigned short*)alloc(128 * 128 * 2);
    (void)ws_size; (void)in_sizes; (void)n_in; (void)out_size;

    const int NB_N = (NNODES + 255) / 256;      // 196
    const int NB_E = (NEDGES + 255) / 256;      // 3125
    const int NB_W = (NNODES * 64 + 255) / 256; // 12500 (wave per node)
    const int NB_G = (NNODES + 63) / 64;        // 782  (gemm 64-row tiles)

    hipMemsetAsync(cnt4, 0, (size_t)NNODES * 16, stream);
    // A: sharded build UNION layernorm (independent work overlapped)
    k_build_ln<<<NB_E + NB_W, 256, 0, stream>>>(ei, ea, cnt4, bucket,
                                                x, g, be, zbuf, NB_E);
    // B: compaction + deg/dis + pads + weight split
    k_prep<<<NB_N + 128, 256, 0, stream>>>(bucket, cnt4, cntp, dis,
                                           W1, W2, Wh1T, Wl1T, Wh2T, Wl2T, NB_N);

    // layer 1
    k_gemm_mfma<<<NB_G, 256, 0, stream>>>(zbuf, Wh1T, Wl1T, dis, hbuf);
    k_aggregate<false><<<NB_W, 256, 0, stream>>>(hbuf, dis, cntp, bucket, b1, zbuf,
                                                 nullptr, nullptr);
    // layer 2
    k_gemm_mfma<<<NB_G, 256, 0, stream>>>(zbuf, Wh2T, Wl2T, dis, hbuf);
    // layer 2 aggregate with fused output GEMV -> h3
    k_aggregate<true><<<NB_W, 256, 0, stream>>>(hbuf, dis, cntp, bucket, b2, nullptr,
                                                W3, h3);
    // output layer scalar aggregation
    k_agg_scalar<<<NB_N, 256, 0, stream>>>(h3, dis, cntp, bucket, b3, out);
}